// Round 9
// baseline (15310.225 us; speedup 1.0000x reference)
//
#include <hip/hip_runtime.h>

// BigARDecoder: persistent-kernel LSTM scan on MI355X.
// B=64, T=256, IN=256, H=1024, G=256, O=64, D=4, GO=320.
//
// R9: staging spans the barrier. gsync uses RAW s_barriers (no vmcnt drain);
// producer waves drain ONLY their 2 state stores via counted WAITV(S) issued
// after staging (FIFO: stores older), then post per-wave flags; out-WGs flag
// immediately. Phase WAITV literals retire leftover staging via trailing-count
// rule; one cheap s_barrier per phase covers partner-wave chunks. Poll = 336
// per-wave flags (3 loads/round). R8's sc0sc1 state loads + register carries
// + 4-wave K-split kept. Identical arithmetic.

typedef unsigned int u32;
typedef unsigned long long u64;
typedef unsigned short u16;
typedef __attribute__((ext_vector_type(8))) __bf16 bf16x8;
typedef __attribute__((ext_vector_type(4))) float f32x4;

#define DEVI __device__ __forceinline__

union FRAG { bf16x8 v; u16 s[8]; u64 q[2]; };
union P4 { u64 q; u16 s[4]; };
union F4 { u64 q[2]; float f[4]; };

DEVI u16 f2bf(float x){ u32 u = __float_as_uint(x); return (u16)((u + 0x7fffu + ((u>>16)&1u)) >> 16); }
DEVI float sigm(float x){ return 1.0f/(1.0f + __expf(-x)); }
DEVI float tanh_(float x){ return 2.0f/(1.0f + __expf(-2.0f*x)) - 1.0f; }
DEVI void ast(void* p, u64 v){ __hip_atomic_store((u64*)p, v, __ATOMIC_RELAXED, __HIP_MEMORY_SCOPE_AGENT); }

// counted asm loads (program order of volatiles == vmcnt FIFO)
DEVI void ld16sc(FRAG& d, const void* p){
  asm volatile("global_load_dwordx4 %0, %1, off sc0 sc1" : "=v"(d.v) : "v"(p));
}
DEVI void ld16(FRAG& d, const void* p){
  asm volatile("global_load_dwordx4 %0, %1, off" : "=v"(d.v) : "v"(p));
}
DEVI void ldf4(f32x4& d, const void* p){
  asm volatile("global_load_dwordx4 %0, %1, off" : "=v"(d) : "v"(p));
}

#define MFMA16(a,b,c) __builtin_amdgcn_mfma_f32_16x16x32_bf16(a, b, c, 0, 0, 0)

#define NWG 168

#define SCHEDB() __builtin_amdgcn_sched_barrier(0)
#define WAITV(n) do{ SCHEDB(); \
  asm volatile("s_waitcnt vmcnt(" #n ")" ::: "memory"); \
  SCHEDB(); }while(0)
#define RBAR() do{ SCHEDB(); __builtin_amdgcn_s_barrier(); SCHEDB(); }while(0)

// poll all 168 WG x 2 per-wave flags of this pipeline (3 loads/round)
#define POLL(epv) \
  if (wave == 0){ \
    for(;;){ \
      u32 a0 = __hip_atomic_load(fbase + lane*32,      __ATOMIC_RELAXED, __HIP_MEMORY_SCOPE_AGENT); \
      u32 a1 = __hip_atomic_load(fbase + (lane+64)*32, __ATOMIC_RELAXED, __HIP_MEMORY_SCOPE_AGENT); \
      u32 a2 = __hip_atomic_load(fbase + i2x*32,       __ATOMIC_RELAXED, __HIP_MEMORY_SCOPE_AGENT); \
      if (__all(a0 >= (epv) && a1 >= (epv) && a2 >= (epv))) break; \
      __builtin_amdgcn_s_sleep(1); \
    } \
  }

// cell-WG sync: raw bar; stage; drain ONLY the 2 state stores (older than
// staging -> WAITV(SLIT)); flag; poll; raw bar. Staging stays in flight.
#define GSYNC_CELL(epv, SLIT, STAGE_STMT) do{ \
  RBAR(); \
  STAGE_STMT; SCHEDB(); \
  if (wave < 2){ WAITV(SLIT); \
    if (lane == 0) __hip_atomic_store(flagp + wave*32, (epv), __ATOMIC_RELAXED, __HIP_MEMORY_SCOPE_AGENT); } \
  SCHEDB(); \
  POLL(epv); \
  RBAR(); \
}while(0)

// out-WG sync: no state stores to order -> flag immediately.
#define GSYNC_OUT(epv, STAGE_STMT) do{ \
  RBAR(); \
  if (wave < 2 && lane == 0) \
    __hip_atomic_store(flagp + wave*32, (epv), __ATOMIC_RELAXED, __HIP_MEMORY_SCOPE_AGENT); \
  STAGE_STMT; SCHEDB(); \
  POLL(epv); \
  RBAR(); \
}while(0)

// ---------------------------------------------------------------------------
// Persistent scan kernel. 168 WGs x 256 threads.
// wg -> (pipe, lw): twins 8 apart (same XCD). lw 0..63: hidden tiles;
// lw 64..83: out-cell / ccA tiles. Wave w = (pair=w>>1 K-half, bt=(pipe<<1)+(w&1)).
// State frag layout (per buffer, 128KB): [btile(4)][ks(32)][bl(16)][kg(4)][8 bf16]
// LDS: 160KB weight chunks. Flags: bar + (pipe*176 + lw*2 + wave)*32.
// ---------------------------------------------------------------------------
__global__ __launch_bounds__(256, 1) void k_scan(
    const float* __restrict__ m_true,
    const u16* __restrict__ Wcell, const u16* __restrict__ Win_h,
    const u16* __restrict__ Win_x, const u16* __restrict__ Wout,
    const u16* __restrict__ WccA,
    const float* __restrict__ b_in, const float* __restrict__ b_cell,
    const float* __restrict__ cAb, const float* __restrict__ b_out,
    const float* __restrict__ b_cc,
    u16* hS, u16* cS, float* cF, float* outp, u32* bar)
{
  const int wg = blockIdx.x;
  const int tid = threadIdx.x;
  const int wave = tid >> 6, lane = tid & 63;

  int pipe, lw;
  if (wg < 160){ pipe = (wg >> 3) & 1; lw = ((wg >> 4) << 3) | (wg & 7); }
  else         { pipe = (wg - 160) >> 2; lw = 80 + ((wg - 160) & 3); }

  const int bl = lane & 15, kg = lane >> 4;
  const int pair = wave >> 1;               // K-half this wave owns
  const int bt = (pipe << 1) + (wave & 1);  // btile this wave owns
  const int b  = (bt << 4) + bl;
  const int swz = (bl & 7) << 4;
  const int foff = ((bl << 2) + kg) << 4;
  const int woff = (bt << 15) + ((lw >> 1) << 10) + (bl << 6) + ((lw & 1) << 5) + (kg << 3);
  u32* flagp = bar + (pipe*176 + lw*2)*32;
  const u32* fbase = bar + pipe*176*32;
  const int i2x = (lane < 40) ? lane + 128 : lane;
  __shared__ __align__(16) u16 ldsW[81920];   // 160KB weight chunks

  f32x4 cprev = {0,0,0,0};   // cell WGs (wave<2): c carry cell3 -> in-cell
  f32x4 ccreg = {0,0,0,0};   // out  WGs (wave<2): cc carry ccA -> out

  auto stage1 = [&](const u16* src, u16* lb, int segs){
    const u16* g = src + (lane << 3);
    u16* l = lb;
    for (int s = 0; s < segs; ++s){
      __builtin_amdgcn_global_load_lds(
          (const __attribute__((address_space(1))) void*)g,
          (__attribute__((address_space(3))) void*)l, 16, 0, 0);
      g += 512; l += 512;
    }
    SCHEDB();
  };
  auto afL = [&](const u16* lb, int row, int kb) -> bf16x8 {
    return *(const bf16x8*)((const char*)lb + row*512 + (kb ^ swz));
  };

  // ---- in-cell phase (lw<64). entry: ch0..3 = Win_h, ch4 = Win_x part1 ----
  auto phase_incell = [&](int t, const u16* hIn, u16* hOut, u16* cOut){
    f32x4 A0={0,0,0,0}, A1={0,0,0,0}, A2={0,0,0,0}, A3={0,0,0,0};
    const char* hf = (const char*)hIn + (bt << 15) + foff;
    const int ksb = pair << 4;
    int jl = (kg << 2), jj = (lw << 4) + jl;
    FRAG sh[2][8], pa[8];
    f32x4 bg0, bg1, bg2, bg3;
    // counted issue: hL1(8) hL2(8) pa(8) bias(4) = 28 (+ leftover staging 40)
    #pragma unroll
    for (int ks = 0; ks < 8; ++ks) ld16sc(sh[0][ks], hf + (ksb + ks)*1024);
    #pragma unroll
    for (int ks = 0; ks < 8; ++ks) ld16sc(sh[1][ks], hf + (ksb + 8 + ks)*1024);
    {
      const char* p2 = (const char*)(Win_x + (size_t)lw*20480 + 16384);
      #pragma unroll
      for (int k2 = 0; k2 < 2; ++k2)
        #pragma unroll
        for (int rb = 0; rb < 4; ++rb)
          ld16(pa[k2*4+rb], p2 + (rb*16 + bl)*128 + (((k2<<6)+(kg<<4)) ^ swz));
    }
    ldf4(bg0, b_in +        jj);
    ldf4(bg1, b_in + 1024 + jj);
    ldf4(bg2, b_in + 2048 + jj);
    ldf4(bg3, b_in + 3072 + jj);
    WAITV(20);                              // staging + hL1 retired
    RBAR();                                 // all waves' chunks in LDS
    const u16* lbA = ldsW + (pair*2)*16384;
    #pragma unroll
    for (int ks = 0; ks < 8; ++ks){
      int kb = (ks << 6) + (kg << 4);
      FRAG a;
      a.v = afL(lbA, bl, kb);      A0 = MFMA16(a.v, sh[0][ks].v, A0);
      a.v = afL(lbA, 16 + bl, kb); A1 = MFMA16(a.v, sh[0][ks].v, A1);
      a.v = afL(lbA, 32 + bl, kb); A2 = MFMA16(a.v, sh[0][ks].v, A2);
      a.v = afL(lbA, 48 + bl, kb); A3 = MFMA16(a.v, sh[0][ks].v, A3);
    }
    WAITV(12);
    const u16* lbB = ldsW + (pair*2+1)*16384;
    #pragma unroll
    for (int ks = 0; ks < 8; ++ks){
      int kb = (ks << 6) + (kg << 4);
      FRAG a;
      a.v = afL(lbB, bl, kb);      A0 = MFMA16(a.v, sh[1][ks].v, A0);
      a.v = afL(lbB, 16 + bl, kb); A1 = MFMA16(a.v, sh[1][ks].v, A1);
      a.v = afL(lbB, 32 + bl, kb); A2 = MFMA16(a.v, sh[1][ks].v, A2);
      a.v = afL(lbB, 48 + bl, kb); A3 = MFMA16(a.v, sh[1][ks].v, A3);
    }
    WAITV(4);                               // pa landed (bias outstanding)
    if (wave >= 2){                         // x contribution (pair B only)
      FRAG xf[10];
      const float* xr = m_true + (size_t)b*81920 + (size_t)(255 - t)*320;
      #pragma unroll
      for (int ks = 0; ks < 10; ++ks){
        int k = (ks << 5) + (kg << 3);
        f32x4 x0 = *(const f32x4*)(xr + k);
        f32x4 x1 = *(const f32x4*)(xr + k + 4);
        xf[ks].s[0]=f2bf(x0[0]); xf[ks].s[1]=f2bf(x0[1]); xf[ks].s[2]=f2bf(x0[2]); xf[ks].s[3]=f2bf(x0[3]);
        xf[ks].s[4]=f2bf(x1[0]); xf[ks].s[5]=f2bf(x1[1]); xf[ks].s[6]=f2bf(x1[2]); xf[ks].s[7]=f2bf(x1[3]);
      }
      const u16* lb4 = ldsW + 65536;
      #pragma unroll
      for (int ks = 0; ks < 8; ++ks){
        int kb = (ks << 6) + (kg << 4);
        FRAG a;
        a.v = afL(lb4, bl, kb);      A0 = MFMA16(a.v, xf[ks].v, A0);
        a.v = afL(lb4, 16 + bl, kb); A1 = MFMA16(a.v, xf[ks].v, A1);
        a.v = afL(lb4, 32 + bl, kb); A2 = MFMA16(a.v, xf[ks].v, A2);
        a.v = afL(lb4, 48 + bl, kb); A3 = MFMA16(a.v, xf[ks].v, A3);
      }
      #pragma unroll
      for (int k2 = 0; k2 < 2; ++k2){
        A0 = MFMA16(pa[k2*4+0].v, xf[8+k2].v, A0);
        A1 = MFMA16(pa[k2*4+1].v, xf[8+k2].v, A1);
        A2 = MFMA16(pa[k2*4+2].v, xf[8+k2].v, A2);
        A3 = MFMA16(pa[k2*4+3].v, xf[8+k2].v, A3);
      }
    }
    __syncthreads();
    float* red = (float*)ldsW;
    if (wave >= 2){
      float* r = red + ((wave&1)*64 + lane)*20;
      *(f32x4*)(r+0) = A0; *(f32x4*)(r+4) = A1;
      *(f32x4*)(r+8) = A2; *(f32x4*)(r+12) = A3;
    }
    __syncthreads();
    if (wave < 2){
      const float* r = red + ((wave&1)*64 + lane)*20;
      A0 += *(const f32x4*)(r+0); A1 += *(const f32x4*)(r+4);
      A2 += *(const f32x4*)(r+8); A3 += *(const f32x4*)(r+12);
      P4 hw, cw;
      #pragma unroll
      for (int rr = 0; rr < 4; ++rr){
        float gi = A0[rr] + bg0[rr];
        float gf = A1[rr] + bg1[rr];
        float gg = A2[rr] + bg2[rr];
        float go = A3[rr] + bg3[rr];
        float cn = sigm(gf)*cprev[rr] + sigm(gi)*tanh_(gg);
        hw.s[rr] = f2bf(sigm(go)*tanh_(cn));
        cw.s[rr] = f2bf(cn);
      }
      ast((char*)hOut + woff, hw.q);
      ast((char*)cOut + woff, cw.q);
    }
  };

  // ---- inner cell phase i (lw<64). entry: ch0..3 = Wcell_i ----
  auto phase_cell = [&](int i, const u16* hIn, const u16* cIn, u16* hOut, u16* cOut, bool last){
    f32x4 A0={0,0,0,0}, A1={0,0,0,0}, A2={0,0,0,0}, A3={0,0,0,0}, A4={0,0,0,0};
    const char* hf  = (const char*)hIn + (bt << 15) + foff;
    const char* cfr = (const char*)cIn + (bt << 15) + foff;
    const int ksb = pair << 4;
    int jl = (kg << 2), jj = (lw << 4) + jl;
    FRAG sh[2][8], sc[2][8];
    f32x4 bg0, bg1, bg2, bg3, bca;
    // counted issue: hL1(8) cL1(8) hL2(8) cL2(8) bias(5) = 37 (+ staging 40)
    #pragma unroll
    for (int ks = 0; ks < 8; ++ks) ld16sc(sh[0][ks], hf  + (ksb + ks)*1024);
    #pragma unroll
    for (int ks = 0; ks < 8; ++ks) ld16sc(sc[0][ks], cfr + (ksb + ks)*1024);
    #pragma unroll
    for (int ks = 0; ks < 8; ++ks) ld16sc(sh[1][ks], hf  + (ksb + 8 + ks)*1024);
    #pragma unroll
    for (int ks = 0; ks < 8; ++ks) ld16sc(sc[1][ks], cfr + (ksb + 8 + ks)*1024);
    ldf4(bg0, b_cell + i*4096 +        jj);
    ldf4(bg1, b_cell + i*4096 + 1024 + jj);
    ldf4(bg2, b_cell + i*4096 + 2048 + jj);
    ldf4(bg3, b_cell + i*4096 + 3072 + jj);
    ldf4(bca, cAb + i*1024 + jj);
    WAITV(21);                              // staging + hL1/cL1 retired
    RBAR();                                 // all waves' chunks in LDS
    const u16* lbA = ldsW + (pair*2)*20480;
    #pragma unroll
    for (int ks = 0; ks < 8; ++ks){
      int kb = (ks << 6) + (kg << 4);
      FRAG a;
      a.v = afL(lbA, bl, kb);      A0 = MFMA16(a.v, sh[0][ks].v, A0);
      a.v = afL(lbA, 16 + bl, kb); A1 = MFMA16(a.v, sh[0][ks].v, A1);
      a.v = afL(lbA, 32 + bl, kb); A2 = MFMA16(a.v, sh[0][ks].v, A2);
      a.v = afL(lbA, 48 + bl, kb); A3 = MFMA16(a.v, sh[0][ks].v, A3);
      a.v = afL(lbA, 64 + bl, kb); A4 = MFMA16(a.v, sc[0][ks].v, A4);
    }
    WAITV(5);
    const u16* lbB = ldsW + (pair*2+1)*20480;
    #pragma unroll
    for (int ks = 0; ks < 8; ++ks){
      int kb = (ks << 6) + (kg << 4);
      FRAG a;
      a.v = afL(lbB, bl, kb);      A0 = MFMA16(a.v, sh[1][ks].v, A0);
      a.v = afL(lbB, 16 + bl, kb); A1 = MFMA16(a.v, sh[1][ks].v, A1);
      a.v = afL(lbB, 32 + bl, kb); A2 = MFMA16(a.v, sh[1][ks].v, A2);
      a.v = afL(lbB, 48 + bl, kb); A3 = MFMA16(a.v, sh[1][ks].v, A3);
      a.v = afL(lbB, 64 + bl, kb); A4 = MFMA16(a.v, sc[1][ks].v, A4);
    }
    __syncthreads();
    float* red = (float*)ldsW;
    if (wave >= 2){
      float* r = red + ((wave&1)*64 + lane)*20;
      *(f32x4*)(r+0) = A0; *(f32x4*)(r+4) = A1;
      *(f32x4*)(r+8) = A2; *(f32x4*)(r+12) = A3; *(f32x4*)(r+16) = A4;
    }
    __syncthreads();
    if (wave < 2){
      const float* r = red + ((wave&1)*64 + lane)*20;
      A0 += *(const f32x4*)(r+0); A1 += *(const f32x4*)(r+4);
      A2 += *(const f32x4*)(r+8); A3 += *(const f32x4*)(r+12);
      A4 += *(const f32x4*)(r+16);
      P4 hw, cw; F4 cf4;
      #pragma unroll
      for (int rr = 0; rr < 4; ++rr){
        float gi = A0[rr] + bg0[rr];
        float gf = A1[rr] + bg1[rr];
        float gg = A2[rr] + bg2[rr];
        float go = A3[rr] + bg3[rr];
        float c1 = A4[rr] + bca[rr];
        float cn = sigm(gf)*c1 + sigm(gi)*tanh_(gg);
        hw.s[rr] = f2bf(sigm(go)*tanh_(cn));
        cw.s[rr] = f2bf(cn);
        cf4.f[rr] = cn;
      }
      ast((char*)hOut + woff, hw.q);
      ast((char*)cOut + woff, cw.q);
      if (last){ cprev[0]=cf4.f[0]; cprev[1]=cf4.f[1]; cprev[2]=cf4.f[2]; cprev[3]=cf4.f[3]; }
    }
  };

  // ---- ccA phase (lw 64..83, with cell i==3). entry: ch0..3 = WccA ----
  auto phase_ccA = [&](const u16* cIn){
    f32x4 A = {0,0,0,0};
    const char* cfr = (const char*)cIn + (bt << 15) + foff;
    const int ksb = pair << 4;
    int jl = (kg << 2), jjo = ((lw - 64) << 4) + jl;
    FRAG sc[2][8];
    f32x4 bcc;
    // counted issue: cL1(8) cL2(8) bcc(1) = 17 (+ staging 8)
    #pragma unroll
    for (int ks = 0; ks < 8; ++ks) ld16sc(sc[0][ks], cfr + (ksb + ks)*1024);
    #pragma unroll
    for (int ks = 0; ks < 8; ++ks) ld16sc(sc[1][ks], cfr + (ksb + 8 + ks)*1024);
    ldf4(bcc, b_cc + jjo);
    WAITV(9);
    RBAR();
    const u16* lbA = ldsW + (pair*2)*4096;
    #pragma unroll
    for (int ks = 0; ks < 8; ++ks){
      int kb = (ks << 6) + (kg << 4);
      FRAG a; a.v = afL(lbA, bl, kb);
      A = MFMA16(a.v, sc[0][ks].v, A);
    }
    WAITV(1);
    const u16* lbB = ldsW + (pair*2+1)*4096;
    #pragma unroll
    for (int ks = 0; ks < 8; ++ks){
      int kb = (ks << 6) + (kg << 4);
      FRAG a; a.v = afL(lbB, bl, kb);
      A = MFMA16(a.v, sc[1][ks].v, A);
    }
    __syncthreads();
    float* red = (float*)ldsW;
    if (wave >= 2) *(f32x4*)(red + ((wave&1)*64 + lane)*20) = A;
    __syncthreads();
    if (wave < 2){
      A += *(const f32x4*)(red + ((wave&1)*64 + lane)*20);
      #pragma unroll
      for (int rr = 0; rr < 4; ++rr) ccreg[rr] = A[rr] + bcc[rr];
    }
  };

  // ---- out-cell phase (lw 64..83). entry: ch0..3 = Wout ----
  auto phase_out = [&](int t, const u16* hIn){
    f32x4 A0={0,0,0,0}, A1={0,0,0,0}, A2={0,0,0,0}, A3={0,0,0,0};
    const char* hf = (const char*)hIn + (bt << 15) + foff;
    const int ksb = pair << 4;
    int jl = (kg << 2), jjo = ((lw - 64) << 4) + jl;
    FRAG sh[2][8];
    f32x4 bg0, bg1, bg2, bg3;
    // counted issue: hL1(8) hL2(8) bias(4) = 20 (+ staging 32)
    #pragma unroll
    for (int ks = 0; ks < 8; ++ks) ld16sc(sh[0][ks], hf + (ksb + ks)*1024);
    #pragma unroll
    for (int ks = 0; ks < 8; ++ks) ld16sc(sh[1][ks], hf + (ksb + 8 + ks)*1024);
    ldf4(bg0, b_out +       jjo);
    ldf4(bg1, b_out + 320 + jjo);
    ldf4(bg2, b_out + 640 + jjo);
    ldf4(bg3, b_out + 960 + jjo);
    WAITV(12);
    RBAR();
    const u16* lbA = ldsW + (pair*2)*16384;
    #pragma unroll
    for (int ks = 0; ks < 8; ++ks){
      int kb = (ks << 6) + (kg << 4);
      FRAG a;
      a.v = afL(lbA, bl, kb);      A0 = MFMA16(a.v, sh[0][ks].v, A0);
      a.v = afL(lbA, 16 + bl, kb); A1 = MFMA16(a.v, sh[0][ks].v, A1);
      a.v = afL(lbA, 32 + bl, kb); A2 = MFMA16(a.v, sh[0][ks].v, A2);
      a.v = afL(lbA, 48 + bl, kb); A3 = MFMA16(a.v, sh[0][ks].v, A3);
    }
    WAITV(4);
    const u16* lbB = ldsW + (pair*2+1)*16384;
    #pragma unroll
    for (int ks = 0; ks < 8; ++ks){
      int kb = (ks << 6) + (kg << 4);
      FRAG a;
      a.v = afL(lbB, bl, kb);      A0 = MFMA16(a.v, sh[1][ks].v, A0);
      a.v = afL(lbB, 16 + bl, kb); A1 = MFMA16(a.v, sh[1][ks].v, A1);
      a.v = afL(lbB, 32 + bl, kb); A2 = MFMA16(a.v, sh[1][ks].v, A2);
      a.v = afL(lbB, 48 + bl, kb); A3 = MFMA16(a.v, sh[1][ks].v, A3);
    }
    __syncthreads();
    float* red = (float*)ldsW;
    if (wave >= 2){
      float* r = red + ((wave&1)*64 + lane)*20;
      *(f32x4*)(r+0) = A0; *(f32x4*)(r+4) = A1;
      *(f32x4*)(r+8) = A2; *(f32x4*)(r+12) = A3;
    }
    __syncthreads();
    if (wave < 2){
      const float* r = red + ((wave&1)*64 + lane)*20;
      A0 += *(const f32x4*)(r+0); A1 += *(const f32x4*)(r+4);
      A2 += *(const f32x4*)(r+8); A3 += *(const f32x4*)(r+12);
      f32x4 ho;
      #pragma unroll
      for (int rr = 0; rr < 4; ++rr){
        float gi = A0[rr] + bg0[rr];
        float gf = A1[rr] + bg1[rr];
        float gg = A2[rr] + bg2[rr];
        float go = A3[rr] + bg3[rr];
        float cn = sigm(gf)*ccreg[rr] + sigm(gi)*tanh_(gg);
        ho[rr] = sigm(go)*tanh_(cn);
      }
      *(f32x4*)(outp + (size_t)b*81920 + (size_t)(t+1)*320 + jjo) = ho;
    }
  };

  // ---- init: cprev from cF, first incell weights (full drain once) ----
  if (lw < 64){
    if (wave < 2){
      int jj = (lw << 4) + (kg << 2);
      cprev = *(const f32x4*)(cF + (size_t)b*1024 + jj);
    }
    stage1(Win_h + ((size_t)lw << 16) + wave*16384, ldsW + wave*16384, 32);
    stage1(Win_x + (size_t)lw*20480 + wave*4096, ldsW + 65536 + wave*4096, 8);
  }
  __syncthreads();
  SCHEDB();

  u16* hB0 = hS;        u16* hB1 = hS + 65536;
  u16* cB0 = cS;        u16* cB1 = cS + 65536;

  u32 ep = 1;
  if (lw < 64){
    phase_incell(0, hB1, hB0, cB0);
    GSYNC_CELL(ep, 40, stage1(Wcell + (size_t)lw*81920 + (size_t)wave*20480, ldsW + wave*20480, 40));
  } else {
    GSYNC_OUT(ep, (void)0);
  }
  ++ep;
  int p = 1;
  #pragma unroll 1
  for (int t = 0; t < 255; ++t){
    #pragma unroll 1
    for (int i = 0; i < 4; ++i){
      u16* hIn = (p & 1) ? hB0 : hB1;  u16* cIn = (p & 1) ? cB0 : cB1;
      u16* hOut = (p & 1) ? hB1 : hB0; u16* cOut = (p & 1) ? cB1 : cB0;
      if (lw < 64){
        phase_cell(i, hIn, cIn, hOut, cOut, i == 3);
        if (i < 3){
          GSYNC_CELL(ep, 40, stage1(Wcell + (size_t)((i+1)*64 + lw)*81920 + (size_t)wave*20480, ldsW + wave*20480, 40));
        } else {
          GSYNC_CELL(ep, 40, {
            stage1(Win_h + ((size_t)lw << 16) + wave*16384, ldsW + wave*16384, 32);
            stage1(Win_x + (size_t)lw*20480 + wave*4096, ldsW + 65536 + wave*4096, 8);
          });
        }
      } else {
        if (i == 3) phase_ccA(cIn);
        if (i == 2){
          GSYNC_OUT(ep, stage1(WccA + ((size_t)(lw-64) << 14) + wave*4096, ldsW + wave*4096, 8));
        } else if (i == 3){
          GSYNC_OUT(ep, stage1(Wout + ((size_t)(lw-64) << 16) + wave*16384, ldsW + wave*16384, 32));
        } else {
          GSYNC_OUT(ep, (void)0);
        }
      }
      ++ep; ++p;
    }
    u16* hIn = (p & 1) ? hB0 : hB1;
    u16* hOut = (p & 1) ? hB1 : hB0; u16* cOut = (p & 1) ? cB1 : cB0;
    if (lw >= 64){
      phase_out(t, hIn);
      GSYNC_OUT(ep, (void)0);
    } else {
      if (t < 254){
        phase_incell(t + 1, hIn, hOut, cOut);
        GSYNC_CELL(ep, 40, stage1(Wcell + (size_t)lw*81920 + (size_t)wave*20480, ldsW + wave*20480, 40));
      } else {
        GSYNC_CELL(ep, 0, (void)0);
      }
    }
    ++ep; ++p;
  }
}

// ---------------------------------------------------------------------------
// Precompute kernels (unchanged)
// ---------------------------------------------------------------------------

__global__ __launch_bounds__(256) void k_dense(const float* __restrict__ X, int xmode,
    const float* __restrict__ W, const float* __restrict__ bias,
    int OD, int ID, int act, int omode, float* outF, u16* outB)
{
  int o = blockIdx.x*4 + (threadIdx.x >> 6);
  if (o >= OD) return;
  int lane = threadIdx.x & 63;
  const float* wr = W + (size_t)o*ID;
  float acc = 0.f;
  if (xmode == 0){ for (int k = 0; k < ID; ++k) acc = fmaf(wr[k], X[(size_t)lane*ID + k], acc); }
  else           { for (int k = 0; k < ID; ++k) acc = fmaf(wr[k], X[(size_t)k*64 + lane], acc); }
  acc += bias[o];
  if (act) acc = acc * sigm(acc);
  if (omode == 0)      outF[(size_t)o*64 + lane] = acc;
  else if (omode == 1){
    int bt = lane >> 4, blx = lane & 15;
    outB[(size_t)bt*16384 + (size_t)(o>>5)*512 + blx*32 + ((o&31)>>3)*8 + (o&7)] = f2bf(acc);
  }
  else if (omode == 2) outF[(size_t)lane*1024 + o] = acc;
  else                 outF[(size_t)lane*81920 + 256 + o] = acc;
}

__global__ void k_zero0(float* out){ out[(size_t)blockIdx.x*81920 + threadIdx.x] = 0.f; }

__global__ __launch_bounds__(256) void k_tr(const float* __restrict__ in, u16* __restrict__ out, int M, int N){
  __shared__ u16 t[64][65];
  int m0 = blockIdx.x << 6, n0 = blockIdx.y << 6;
  int c = threadIdx.x & 63, rq = threadIdx.x >> 6;
  for (int rr = 0; rr < 16; ++rr){
    int r = (rq << 4) + rr;
    t[r][c] = f2bf(in[(size_t)(m0 + r)*N + n0 + c]);
  }
  __syncthreads();
  for (int rr = 0; rr < 16; ++rr){
    int r = (rq << 4) + rr;
    out[(size_t)(n0 + r)*M + m0 + c] = t[c][r];
  }
}

__global__ __launch_bounds__(256) void k_fuse(const float* __restrict__ Whh, const float* __restrict__ Wih,
    const u16* __restrict__ BT, int KM, int mode, u16* __restrict__ dst)
{
  int bx = blockIdx.x, by = blockIdx.y, bz = blockIdx.z;
  int lane = threadIdx.x & 63, wv = threadIdx.x >> 6;
  int bl = lane & 15, kg = lane >> 4;
  int jbase = (mode == 0) ? bz*1024 : ((mode == 1) ? bz*320 : 0);
  int jrow = jbase + bx*16 + bl;
  int k2c = by*64 + wv*16 + bl;
  f32x4 acc = {0,0,0,0};
  for (int m0 = 0; m0 < KM; m0 += 32){
    f32x4 wa0 = *(const f32x4*)(Whh + (size_t)jrow*KM + m0 + (kg << 3));
    f32x4 wa1 = *(const f32x4*)(Whh + (size_t)jrow*KM + m0 + (kg << 3) + 4);
    FRAG a;
    a.s[0]=f2bf(wa0[0]); a.s[1]=f2bf(wa0[1]); a.s[2]=f2bf(wa0[2]); a.s[3]=f2bf(wa0[3]);
    a.s[4]=f2bf(wa1[0]); a.s[5]=f2bf(wa1[1]); a.s[6]=f2bf(wa1[2]); a.s[7]=f2bf(wa1[3]);
    FRAG bb; bb.v = *(const bf16x8*)(BT + (size_t)k2c*KM + m0 + (kg << 3));
    acc = MFMA16(a.v, bb.v, acc);
  }
  #pragma unroll
  for (int r = 0; r < 4; ++r){
    int jl = (kg << 2) + r;
    int jg = jbase + bx*16 + jl;
    float v = acc[r];
    if (mode < 2) v += Wih[(size_t)jg*1024 + k2c];
    int re = (mode == 2) ? jl : (bz*16 + jl);
    int c = k2c >> 8, kl = k2c & 255;
    size_t pos;
    if (mode == 0)      pos = (size_t)bx*81920 + c*20480 + re*256 + (kl ^ ((re&7)<<3));
    else if (mode == 1) pos = (size_t)bx*65536 + c*16384 + re*256 + (kl ^ ((re&7)<<3));
    else                pos = (size_t)bx*16384 + c*4096  + re*256 + (kl ^ ((re&7)<<3));
    dst[pos] = f2bf(v);
  }
}

__global__ void k_pack_winh(const float* __restrict__ src, u16* __restrict__ dst){
  int id = blockIdx.x*256 + threadIdx.x;
  int j = id >> 10, k = id & 1023;
  int g = j >> 10, jj = j & 1023;
  int w = jj >> 4, r = (g << 4) + (jj & 15);
  int c = k >> 8, kl = k & 255;
  dst[(size_t)w*65536 + c*16384 + r*256 + (kl ^ ((r&7)<<3))] = f2bf(src[id]);
}

__global__ void k_pack_winx(const float* __restrict__ src, u16* __restrict__ dst){
  int j = blockIdx.x, k = threadIdx.x;
  int g = j >> 10, jj = j & 1023;
  int w = jj >> 4, r = (g << 4) + (jj & 15);
  float v = src[(size_t)j*320 + k];
  size_t pos;
  if (k < 256) pos = (size_t)w*20480 + r*256 + (k ^ ((r&7)<<3));
  else         pos = (size_t)w*20480 + 16384 + r*64 + ((k - 256) ^ ((r&7)<<3));
  dst[pos] = f2bf(v);
}

__global__ void k_pack_ca(const float* __restrict__ src, u16* __restrict__ dst){
  int id = blockIdx.x*256 + threadIdx.x;
  int jj = id >> 10, k = id & 1023;
  int w = jj >> 4, r = 64 + (jj & 15);
  int c = k >> 8, kl = k & 255;
  dst[(size_t)w*81920 + c*20480 + r*256 + (kl ^ ((r&7)<<3))] = f2bf(src[id]);
}

__global__ __launch_bounds__(256) void k_bias(const float* __restrict__ A, const float* __restrict__ x,
    const float* __restrict__ a1, const float* __restrict__ a2, float* __restrict__ o, int NJ, int K)
{
  int j = blockIdx.x*4 + (threadIdx.x >> 6);
  if (j >= NJ) return;
  int lane = threadIdx.x & 63;
  float acc = 0.f;
  if (A) for (int k = lane; k < K; k += 64) acc += A[(size_t)j*K + k]*x[k];
  for (int off = 32; off; off >>= 1) acc += __shfl_down(acc, off);
  if (lane == 0) o[j] = acc + (a1 ? a1[j] : 0.f) + (a2 ? a2[j] : 0.f);
}

// ---------------------------------------------------------------------------
extern "C" void kernel_launch(void* const* d_in, const int* in_sizes, int n_in,
                              void* d_out, int out_size, void* d_ws, size_t ws_size,
                              hipStream_t stream)
{
  (void)in_sizes; (void)n_in; (void)out_size;
  const float* z      = (const float*)d_in[0];
  const float* m_true = (const float*)d_in[1];
  const float* eh_W1=(const float*)d_in[2],  *eh_b1=(const float*)d_in[3];
  const float* eh_W2=(const float*)d_in[4],  *eh_b2=(const float*)d_in[5];
  const float* eh_W3=(const float*)d_in[6],  *eh_b3=(const float*)d_in[7];
  const float* ec_W1=(const float*)d_in[8],  *ec_b1=(const float*)d_in[9];
  const float* ec_W2=(const float*)d_in[10], *ec_b2=(const float*)d_in[11];
  const float* ec_W3=(const float*)d_in[12], *ec_b3=(const float*)d_in[13];
  const float* ex_W1=(const float*)d_in[14], *ex_b1=(const float*)d_in[15];
  const float* ex_W2=(const float*)d_in[16], *ex_b2=(const float*)d_in[17];
  const float* ex_W3=(const float*)d_in[18], *ex_b3=(const float*)d_in[19];
  const float* in_Wih=(const float*)d_in[20], *in_Whh=(const float*)d_in[21];
  const float* in_bih=(const float*)d_in[22], *in_bhh=(const float*)d_in[23];
  const float* r_Wih=(const float*)d_in[24],  *r_Whh=(const float*)d_in[25];
  const float* r_bih=(const float*)d_in[26],  *r_bhh=(const float*)d_in[27];
  const float* hA_W=(const float*)d_in[28],   *hA_b=(const float*)d_in[29];
  const float* cA_W=(const float*)d_in[30],   *cA_b=(const float*)d_in[31];
  const float* lastH_W=(const float*)d_in[32], *lastH_b=(const float*)d_in[33];
  const float* lastC_W=(const float*)d_in[34], *lastC_b=(const float*)d_in[35];
  const float* out_Wih=(const float*)d_in[36], *out_Whh=(const float*)d_in[37];
  const float* out_bih=(const float*)d_in[38], *out_bhh=(const float*)d_in[39];
  float* out = (float*)d_out;

  char* wsb = (char*)d_ws;
  size_t off = 0;
  auto alloc = [&](size_t bytes)->char*{
    char* p = wsb + off; off = (off + bytes + 255) & ~(size_t)255; return p;
  };
  u32* bar    = (u32*)alloc(512*32*4);
  u16* hS     = (u16*)alloc(2*64*1024*2);
  u16* cS     = (u16*)alloc(2*64*1024*2);
  float* cF   = (float*)alloc(64*1024*4);
  float* b_in = (float*)alloc(4096*4);
  float* b_cell=(float*)alloc(4*4096*4);
  float* b_out= (float*)alloc(1280*4);
  float* b_cc = (float*)alloc(320*4);
  float* t1   = (float*)alloc(1024*64*4);
  float* t2   = (float*)alloc(1024*64*4);
  u16* Tbuf   = (u16*)alloc((size_t)1024*1024*2);
  u16* Win_h  = (u16*)alloc((size_t)64*65536*2);
  u16* Win_x  = (u16*)alloc((size_t)64*20480*2);
  u16* Wcell  = (u16*)alloc((size_t)4*64*81920*2);
  u16* Wout   = (u16*)alloc((size_t)20*65536*2);
  u16* WccA   = (u16*)alloc((size_t)20*16384*2);
  if (off > ws_size) return;

  hipMemsetAsync(bar, 0, 512*32*4, stream);

  k_dense<<<256,256,0,stream>>>(z, 0, eh_W1, eh_b1, 1024, 256, 1, 0, t1, nullptr);
  k_dense<<<256,256,0,stream>>>(t1,1, eh_W2, eh_b2, 1024,1024, 1, 0, t2, nullptr);
  k_dense<<<256,256,0,stream>>>(t2,1, eh_W3, eh_b3, 1024,1024, 0, 1, nullptr, hS + 65536);
  k_dense<<<256,256,0,stream>>>(z, 0, ec_W1, ec_b1, 1024, 256, 1, 0, t1, nullptr);
  k_dense<<<256,256,0,stream>>>(t1,1, ec_W2, ec_b2, 1024,1024, 1, 0, t2, nullptr);
  k_dense<<<256,256,0,stream>>>(t2,1, ec_W3, ec_b3, 1024,1024, 0, 2, cF, nullptr);
  k_dense<<<256,256,0,stream>>>(z, 0, ex_W1, ex_b1, 1024, 256, 1, 0, t1, nullptr);
  k_dense<<<256,256,0,stream>>>(t1,1, ex_W2, ex_b2, 1024,1024, 1, 0, t2, nullptr);
  k_dense<<<16 ,256,0,stream>>>(t2,1, ex_W3, ex_b3,   64,1024, 0, 3, out, nullptr);
  k_zero0<<<64,256,0,stream>>>(out);

  k_pack_winh<<<16384,256,0,stream>>>(in_Whh, Win_h);
  k_pack_winx<<<4096,320,0,stream>>>(in_Wih, Win_x);
  for (int i = 0; i < 4; ++i)
    k_pack_ca<<<4096,256,0,stream>>>(cA_W + (size_t)i*1024*1024, Wcell + (size_t)i*64*81920);

  for (int i = 0; i < 4; ++i){
    k_tr<<<dim3(16,16),256,0,stream>>>(hA_W + (size_t)i*1024*1024, Tbuf, 1024, 1024);
    k_fuse<<<dim3(64,16,4),256,0,stream>>>(r_Whh + (size_t)i*4096*1024,
                                           r_Wih + (size_t)i*4096*1024,
                                           Tbuf, 1024, 0, Wcell + (size_t)i*64*81920);
  }
  k_tr<<<dim3(5,16),256,0,stream>>>(lastH_W, Tbuf, 320, 1024);
  k_fuse<<<dim3(20,16,4),256,0,stream>>>(out_Whh, out_Wih, Tbuf, 320, 1, Wout);
  k_tr<<<dim3(16,16),256,0,stream>>>(cA_W + (size_t)3*1024*1024, Tbuf, 1024, 1024);
  k_fuse<<<dim3(20,16,1),256,0,stream>>>(lastC_W, nullptr, Tbuf, 1024, 2, WccA);

  k_bias<<<1024,256,0,stream>>>(nullptr, nullptr, in_bih, in_bhh, b_in, 4096, 0);
  for (int i = 0; i < 4; ++i)
    k_bias<<<1024,256,0,stream>>>(r_Whh + (size_t)i*4096*1024, hA_b + i*1024,
                                  r_bih + i*4096, r_bhh + i*4096, b_cell + i*4096, 4096, 1024);
  k_bias<<<320,256,0,stream>>>(out_Whh, lastH_b, out_bih, out_bhh, b_out, 1280, 320);
  k_bias<<<80 ,256,0,stream>>>(lastC_W, cA_b + 3*1024, lastC_b, nullptr, b_cc, 320, 1024);

  k_scan<<<NWG,256,0,stream>>>(m_true, Wcell, Win_h, Win_x, Wout, WccA,
                               b_in, b_cell, cA_b, b_out, b_cc,
                               hS, cS, cF, out, bar);
}

// Round 11
// 12380.023 us; speedup vs baseline: 1.2367x; 1.2367x over previous
//
#include <hip/hip_runtime.h>

// BigARDecoder: persistent-kernel LSTM scan on MI355X.
// B=64, T=256, IN=256, H=1024, G=256, O=64, D=4, GO=320.
//
// R11 = R10 with k_cvt grid fixed (4096 blocks, was 16384 -> 4x OOB write
// that corrupted the workspace and crashed). Changes vs R8:
// (a) barrier-window staging moved to waves 1-3; wave 0 polls with an empty
//     vmcnt queue (atomic flag loads emit vmcnt(0) waits -> R8's poll was
//     serialized behind wave0's own staging);
// (b) precompute: r_Whh pre-converted to bf16 (k_cvt) so k_fuse loads the
//     A operand directly (halves A bytes, kills per-use cvt VALU).

typedef unsigned int u32;
typedef unsigned long long u64;
typedef unsigned short u16;
typedef __attribute__((ext_vector_type(8))) __bf16 bf16x8;
typedef __attribute__((ext_vector_type(4))) float f32x4;

#define DEVI __device__ __forceinline__

union FRAG { bf16x8 v; u16 s[8]; u64 q[2]; };
union P4 { u64 q; u16 s[4]; };
union F4 { u64 q[2]; float f[4]; };

DEVI u16 f2bf(float x){ u32 u = __float_as_uint(x); return (u16)((u + 0x7fffu + ((u>>16)&1u)) >> 16); }
DEVI float sigm(float x){ return 1.0f/(1.0f + __expf(-x)); }
DEVI float tanh_(float x){ return 2.0f/(1.0f + __expf(-2.0f*x)) - 1.0f; }
DEVI void ast(void* p, u64 v){ __hip_atomic_store((u64*)p, v, __ATOMIC_RELAXED, __HIP_MEMORY_SCOPE_AGENT); }

// counted asm loads (program order of volatiles == vmcnt FIFO)
DEVI void ld16sc(FRAG& d, const void* p){
  asm volatile("global_load_dwordx4 %0, %1, off sc0 sc1" : "=v"(d.v) : "v"(p));
}
DEVI void ld16(FRAG& d, const void* p){
  asm volatile("global_load_dwordx4 %0, %1, off" : "=v"(d.v) : "v"(p));
}
DEVI void ldf4(f32x4& d, const void* p){
  asm volatile("global_load_dwordx4 %0, %1, off" : "=v"(d) : "v"(p));
}

#define MFMA16(a,b,c) __builtin_amdgcn_mfma_f32_16x16x32_bf16(a, b, c, 0, 0, 0)

#define NWG 168

#define SCHEDB() __builtin_amdgcn_sched_barrier(0)
#define WAITV(n) do{ SCHEDB(); \
  asm volatile("s_waitcnt vmcnt(" #n ")" ::: "memory"); \
  SCHEDB(); }while(0)

// ---------------------------------------------------------------------------
// Persistent scan kernel. 168 WGs x 256 threads (no master).
// wg -> (pipe, lw): twins 8 apart (same XCD). lw 0..63: hidden tiles;
// lw 64..83: out-cell / ccA tiles. Wave w = (pair=w>>1 K-half, bt=(pipe<<1)+(w&1)).
// State frag layout (per buffer, 128KB): [btile(4)][ks(32)][bl(16)][kg(4)][8 bf16]
// LDS: 160KB weight chunks. Flags: bar + (pipe*128 + lw)*32 (128B lines).
// ---------------------------------------------------------------------------
__global__ __launch_bounds__(256, 1) void k_scan(
    const float* __restrict__ m_true,
    const u16* __restrict__ Wcell, const u16* __restrict__ Win_h,
    const u16* __restrict__ Win_x, const u16* __restrict__ Wout,
    const u16* __restrict__ WccA,
    const float* __restrict__ b_in, const float* __restrict__ b_cell,
    const float* __restrict__ cAb, const float* __restrict__ b_out,
    const float* __restrict__ b_cc,
    u16* hS, u16* cS, float* cF, float* outp, u32* bar)
{
  const int wg = blockIdx.x;
  const int tid = threadIdx.x;
  const int wave = tid >> 6, lane = tid & 63;

  int pipe, lw;
  if (wg < 160){ pipe = (wg >> 3) & 1; lw = ((wg >> 4) << 3) | (wg & 7); }
  else         { pipe = (wg - 160) >> 2; lw = 80 + ((wg - 160) & 3); }

  const int bl = lane & 15, kg = lane >> 4;
  const int pair = wave >> 1;               // K-half this wave owns
  const int bt = (pipe << 1) + (wave & 1);  // btile this wave owns
  const int b  = (bt << 4) + bl;
  const int swz = (bl & 7) << 4;
  const int foff = ((bl << 2) + kg) << 4;
  const int woff = (bt << 15) + ((lw >> 1) << 10) + (bl << 6) + ((lw & 1) << 5) + (kg << 3);
  u32* flagp = bar + (pipe*128 + lw)*32;
  const u32* fbase = bar + pipe*128*32;
  const int i2 = (lane < 20) ? 64 + lane : lane;   // poll coverage 0..83
  __shared__ __align__(16) u16 ldsW[81920];   // 160KB weight chunks

  f32x4 cprev = {0,0,0,0};   // cell WGs (wave<2): c carry cell3 -> in-cell
  f32x4 ccreg = {0,0,0,0};   // out  WGs (wave<2): cc carry ccA -> out

  auto stage1 = [&](const u16* src, u16* lb, int segs){
    const u16* g = src + (lane << 3);
    u16* l = lb;
    for (int s = 0; s < segs; ++s){
      __builtin_amdgcn_global_load_lds(
          (const __attribute__((address_space(1))) void*)g,
          (__attribute__((address_space(3))) void*)l, 16, 0, 0);
      g += 512; l += 512;
    }
    SCHEDB();
  };
  auto afL = [&](const u16* lb, int row, int kb) -> bf16x8 {
    return *(const bf16x8*)((const char*)lb + row*512 + (kb ^ swz));
  };

  // masterless barrier: flag bump; waves 1-3 stage next-phase weights;
  // wave 0 polls with EMPTY vmcnt queue (fast flag reads).
  auto gsync = [&](u32 ep, const u16* src, u16* dst, int segs){
    SCHEDB();
    __syncthreads();                  // per-wave vmcnt(0): state stores acked
    if (tid == 0)
      __hip_atomic_store(flagp, ep, __ATOMIC_RELAXED, __HIP_MEMORY_SCOPE_AGENT);
    SCHEDB();
    if (src) stage1(src, dst, segs);
    SCHEDB();
    if (wave == 0){
      for(;;){
        u32 a = __hip_atomic_load(fbase + lane*32, __ATOMIC_RELAXED, __HIP_MEMORY_SCOPE_AGENT);
        u32 c2 = __hip_atomic_load(fbase + i2*32, __ATOMIC_RELAXED, __HIP_MEMORY_SCOPE_AGENT);
        if (__all(a >= ep && c2 >= ep)) break;
        __builtin_amdgcn_s_sleep(1);
      }
    }
    __syncthreads();                  // broadcast + drain weight stage
    SCHEDB();
  };

  // per-wave staging range helpers (waves 1-3 only)
  auto gs_cell = [&](u32 ep2, const u16* blk){        // 160 segs
    const u16* s = nullptr; u16* d = nullptr; int n = 0;
    if (wave == 1){ s = blk;          d = ldsW;          n = 54; }
    else if (wave == 2){ s = blk + 27648;  d = ldsW + 27648;  n = 53; }
    else if (wave == 3){ s = blk + 54784;  d = ldsW + 54784;  n = 53; }
    gsync(ep2, s, d, n);
  };
  auto gs_incell = [&](u32 ep2){                      // 128 + 32 segs
    const u16* s = nullptr; u16* d = nullptr; int n = 0;
    if (wave == 1){ s = Win_h + ((size_t)lw << 16);         d = ldsW;         n = 64; }
    else if (wave == 2){ s = Win_h + ((size_t)lw << 16) + 32768; d = ldsW + 32768; n = 64; }
    else if (wave == 3){ s = Win_x + (size_t)lw*20480;      d = ldsW + 65536; n = 32; }
    gsync(ep2, s, d, n);
  };
  auto gs_out = [&](u32 ep2){                         // 128 segs
    const u16* base = Wout + ((size_t)(lw - 64) << 16);
    const u16* s = nullptr; u16* d = nullptr; int n = 0;
    if (wave == 1){ s = base;          d = ldsW;          n = 43; }
    else if (wave == 2){ s = base + 22016;  d = ldsW + 22016;  n = 43; }
    else if (wave == 3){ s = base + 44032;  d = ldsW + 44032;  n = 42; }
    gsync(ep2, s, d, n);
  };
  auto gs_ccA = [&](u32 ep2){                         // 32 segs
    const u16* base = WccA + ((size_t)(lw - 64) << 14);
    const u16* s = nullptr; u16* d = nullptr; int n = 0;
    if (wave == 1){ s = base;          d = ldsW;          n = 11; }
    else if (wave == 2){ s = base + 5632;   d = ldsW + 5632;   n = 11; }
    else if (wave == 3){ s = base + 11264;  d = ldsW + 11264;  n = 10; }
    gsync(ep2, s, d, n);
  };

  // ---- in-cell phase (lw<64). entry: ch0..3 = Win_h, ch4 = Win_x part1 ----
  auto phase_incell = [&](int t, const u16* hIn, u16* hOut, u16* cOut){
    f32x4 A0={0,0,0,0}, A1={0,0,0,0}, A2={0,0,0,0}, A3={0,0,0,0};
    const char* hf = (const char*)hIn + (bt << 15) + foff;
    const int ksb = pair << 4;
    int jl = (kg << 2), jj = (lw << 4) + jl;
    FRAG sh[2][8], pa[8];
    f32x4 bg0, bg1, bg2, bg3;
    // counted issue: hL1(8) hL2(8) pa(8) bias(4) = 28
    #pragma unroll
    for (int ks = 0; ks < 8; ++ks) ld16sc(sh[0][ks], hf + (ksb + ks)*1024);
    #pragma unroll
    for (int ks = 0; ks < 8; ++ks) ld16sc(sh[1][ks], hf + (ksb + 8 + ks)*1024);
    {
      const char* p2 = (const char*)(Win_x + (size_t)lw*20480 + 16384);
      #pragma unroll
      for (int k2 = 0; k2 < 2; ++k2)
        #pragma unroll
        for (int rb = 0; rb < 4; ++rb)
          ld16(pa[k2*4+rb], p2 + (rb*16 + bl)*128 + (((k2<<6)+(kg<<4)) ^ swz));
    }
    ldf4(bg0, b_in +        jj);
    ldf4(bg1, b_in + 1024 + jj);
    ldf4(bg2, b_in + 2048 + jj);
    ldf4(bg3, b_in + 3072 + jj);
    WAITV(20);
    const u16* lbA = ldsW + (pair*2)*16384;
    #pragma unroll
    for (int ks = 0; ks < 8; ++ks){
      int kb = (ks << 6) + (kg << 4);
      FRAG a;
      a.v = afL(lbA, bl, kb);      A0 = MFMA16(a.v, sh[0][ks].v, A0);
      a.v = afL(lbA, 16 + bl, kb); A1 = MFMA16(a.v, sh[0][ks].v, A1);
      a.v = afL(lbA, 32 + bl, kb); A2 = MFMA16(a.v, sh[0][ks].v, A2);
      a.v = afL(lbA, 48 + bl, kb); A3 = MFMA16(a.v, sh[0][ks].v, A3);
    }
    WAITV(12);
    const u16* lbB = ldsW + (pair*2+1)*16384;
    #pragma unroll
    for (int ks = 0; ks < 8; ++ks){
      int kb = (ks << 6) + (kg << 4);
      FRAG a;
      a.v = afL(lbB, bl, kb);      A0 = MFMA16(a.v, sh[1][ks].v, A0);
      a.v = afL(lbB, 16 + bl, kb); A1 = MFMA16(a.v, sh[1][ks].v, A1);
      a.v = afL(lbB, 32 + bl, kb); A2 = MFMA16(a.v, sh[1][ks].v, A2);
      a.v = afL(lbB, 48 + bl, kb); A3 = MFMA16(a.v, sh[1][ks].v, A3);
    }
    WAITV(4);                               // pa landed (bias outstanding)
    if (wave >= 2){                         // x contribution (pair B only)
      FRAG xf[10];
      const float* xr = m_true + (size_t)b*81920 + (size_t)(255 - t)*320;
      #pragma unroll
      for (int ks = 0; ks < 10; ++ks){
        int k = (ks << 5) + (kg << 3);
        f32x4 x0 = *(const f32x4*)(xr + k);
        f32x4 x1 = *(const f32x4*)(xr + k + 4);
        xf[ks].s[0]=f2bf(x0[0]); xf[ks].s[1]=f2bf(x0[1]); xf[ks].s[2]=f2bf(x0[2]); xf[ks].s[3]=f2bf(x0[3]);
        xf[ks].s[4]=f2bf(x1[0]); xf[ks].s[5]=f2bf(x1[1]); xf[ks].s[6]=f2bf(x1[2]); xf[ks].s[7]=f2bf(x1[3]);
      }
      const u16* lb4 = ldsW + 65536;
      #pragma unroll
      for (int ks = 0; ks < 8; ++ks){
        int kb = (ks << 6) + (kg << 4);
        FRAG a;
        a.v = afL(lb4, bl, kb);      A0 = MFMA16(a.v, xf[ks].v, A0);
        a.v = afL(lb4, 16 + bl, kb); A1 = MFMA16(a.v, xf[ks].v, A1);
        a.v = afL(lb4, 32 + bl, kb); A2 = MFMA16(a.v, xf[ks].v, A2);
        a.v = afL(lb4, 48 + bl, kb); A3 = MFMA16(a.v, xf[ks].v, A3);
      }
      #pragma unroll
      for (int k2 = 0; k2 < 2; ++k2){
        A0 = MFMA16(pa[k2*4+0].v, xf[8+k2].v, A0);
        A1 = MFMA16(pa[k2*4+1].v, xf[8+k2].v, A1);
        A2 = MFMA16(pa[k2*4+2].v, xf[8+k2].v, A2);
        A3 = MFMA16(pa[k2*4+3].v, xf[8+k2].v, A3);
      }
    }
    __syncthreads();                        // also drains bias/xf
    float* red = (float*)ldsW;
    if (wave >= 2){
      float* r = red + ((wave&1)*64 + lane)*20;
      *(f32x4*)(r+0) = A0; *(f32x4*)(r+4) = A1;
      *(f32x4*)(r+8) = A2; *(f32x4*)(r+12) = A3;
    }
    __syncthreads();
    if (wave < 2){
      const float* r = red + ((wave&1)*64 + lane)*20;
      A0 += *(const f32x4*)(r+0); A1 += *(const f32x4*)(r+4);
      A2 += *(const f32x4*)(r+8); A3 += *(const f32x4*)(r+12);
      P4 hw, cw;
      #pragma unroll
      for (int rr = 0; rr < 4; ++rr){
        float gi = A0[rr] + bg0[rr];
        float gf = A1[rr] + bg1[rr];
        float gg = A2[rr] + bg2[rr];
        float go = A3[rr] + bg3[rr];
        float cn = sigm(gf)*cprev[rr] + sigm(gi)*tanh_(gg);
        hw.s[rr] = f2bf(sigm(go)*tanh_(cn));
        cw.s[rr] = f2bf(cn);
      }
      ast((char*)hOut + woff, hw.q);
      ast((char*)cOut + woff, cw.q);
    }
  };

  // ---- inner cell phase i (lw<64). entry: ch0..3 = Wcell_i ----
  auto phase_cell = [&](int i, const u16* hIn, const u16* cIn, u16* hOut, u16* cOut, bool last){
    f32x4 A0={0,0,0,0}, A1={0,0,0,0}, A2={0,0,0,0}, A3={0,0,0,0}, A4={0,0,0,0};
    const char* hf  = (const char*)hIn + (bt << 15) + foff;
    const char* cfr = (const char*)cIn + (bt << 15) + foff;
    const int ksb = pair << 4;
    int jl = (kg << 2), jj = (lw << 4) + jl;
    FRAG sh[2][8], sc[2][8];
    f32x4 bg0, bg1, bg2, bg3, bca;
    // counted issue: hL1(8) cL1(8) hL2(8) cL2(8) bias(5) = 37
    #pragma unroll
    for (int ks = 0; ks < 8; ++ks) ld16sc(sh[0][ks], hf  + (ksb + ks)*1024);
    #pragma unroll
    for (int ks = 0; ks < 8; ++ks) ld16sc(sc[0][ks], cfr + (ksb + ks)*1024);
    #pragma unroll
    for (int ks = 0; ks < 8; ++ks) ld16sc(sh[1][ks], hf  + (ksb + 8 + ks)*1024);
    #pragma unroll
    for (int ks = 0; ks < 8; ++ks) ld16sc(sc[1][ks], cfr + (ksb + 8 + ks)*1024);
    ldf4(bg0, b_cell + i*4096 +        jj);
    ldf4(bg1, b_cell + i*4096 + 1024 + jj);
    ldf4(bg2, b_cell + i*4096 + 2048 + jj);
    ldf4(bg3, b_cell + i*4096 + 3072 + jj);
    ldf4(bca, cAb + i*1024 + jj);
    WAITV(21);
    const u16* lbA = ldsW + (pair*2)*20480;
    #pragma unroll
    for (int ks = 0; ks < 8; ++ks){
      int kb = (ks << 6) + (kg << 4);
      FRAG a;
      a.v = afL(lbA, bl, kb);      A0 = MFMA16(a.v, sh[0][ks].v, A0);
      a.v = afL(lbA, 16 + bl, kb); A1 = MFMA16(a.v, sh[0][ks].v, A1);
      a.v = afL(lbA, 32 + bl, kb); A2 = MFMA16(a.v, sh[0][ks].v, A2);
      a.v = afL(lbA, 48 + bl, kb); A3 = MFMA16(a.v, sh[0][ks].v, A3);
      a.v = afL(lbA, 64 + bl, kb); A4 = MFMA16(a.v, sc[0][ks].v, A4);
    }
    WAITV(5);
    const u16* lbB = ldsW + (pair*2+1)*20480;
    #pragma unroll
    for (int ks = 0; ks < 8; ++ks){
      int kb = (ks << 6) + (kg << 4);
      FRAG a;
      a.v = afL(lbB, bl, kb);      A0 = MFMA16(a.v, sh[1][ks].v, A0);
      a.v = afL(lbB, 16 + bl, kb); A1 = MFMA16(a.v, sh[1][ks].v, A1);
      a.v = afL(lbB, 32 + bl, kb); A2 = MFMA16(a.v, sh[1][ks].v, A2);
      a.v = afL(lbB, 48 + bl, kb); A3 = MFMA16(a.v, sh[1][ks].v, A3);
      a.v = afL(lbB, 64 + bl, kb); A4 = MFMA16(a.v, sc[1][ks].v, A4);
    }
    __syncthreads();
    float* red = (float*)ldsW;
    if (wave >= 2){
      float* r = red + ((wave&1)*64 + lane)*20;
      *(f32x4*)(r+0) = A0; *(f32x4*)(r+4) = A1;
      *(f32x4*)(r+8) = A2; *(f32x4*)(r+12) = A3; *(f32x4*)(r+16) = A4;
    }
    __syncthreads();
    if (wave < 2){
      const float* r = red + ((wave&1)*64 + lane)*20;
      A0 += *(const f32x4*)(r+0); A1 += *(const f32x4*)(r+4);
      A2 += *(const f32x4*)(r+8); A3 += *(const f32x4*)(r+12);
      A4 += *(const f32x4*)(r+16);
      P4 hw, cw; F4 cf4;
      #pragma unroll
      for (int rr = 0; rr < 4; ++rr){
        float gi = A0[rr] + bg0[rr];
        float gf = A1[rr] + bg1[rr];
        float gg = A2[rr] + bg2[rr];
        float go = A3[rr] + bg3[rr];
        float c1 = A4[rr] + bca[rr];
        float cn = sigm(gf)*c1 + sigm(gi)*tanh_(gg);
        hw.s[rr] = f2bf(sigm(go)*tanh_(cn));
        cw.s[rr] = f2bf(cn);
        cf4.f[rr] = cn;
      }
      ast((char*)hOut + woff, hw.q);
      ast((char*)cOut + woff, cw.q);
      if (last){ cprev[0]=cf4.f[0]; cprev[1]=cf4.f[1]; cprev[2]=cf4.f[2]; cprev[3]=cf4.f[3]; }
    }
  };

  // ---- ccA phase (lw 64..83, with cell i==3). entry: ch0..3 = WccA ----
  auto phase_ccA = [&](const u16* cIn){
    f32x4 A = {0,0,0,0};
    const char* cfr = (const char*)cIn + (bt << 15) + foff;
    const int ksb = pair << 4;
    int jl = (kg << 2), jjo = ((lw - 64) << 4) + jl;
    FRAG sc[2][8];
    f32x4 bcc;
    // counted issue: cL1(8) cL2(8) bcc(1) = 17
    #pragma unroll
    for (int ks = 0; ks < 8; ++ks) ld16sc(sc[0][ks], cfr + (ksb + ks)*1024);
    #pragma unroll
    for (int ks = 0; ks < 8; ++ks) ld16sc(sc[1][ks], cfr + (ksb + 8 + ks)*1024);
    ldf4(bcc, b_cc + jjo);
    WAITV(9);
    const u16* lbA = ldsW + (pair*2)*4096;
    #pragma unroll
    for (int ks = 0; ks < 8; ++ks){
      int kb = (ks << 6) + (kg << 4);
      FRAG a; a.v = afL(lbA, bl, kb);
      A = MFMA16(a.v, sc[0][ks].v, A);
    }
    WAITV(1);
    const u16* lbB = ldsW + (pair*2+1)*4096;
    #pragma unroll
    for (int ks = 0; ks < 8; ++ks){
      int kb = (ks << 6) + (kg << 4);
      FRAG a; a.v = afL(lbB, bl, kb);
      A = MFMA16(a.v, sc[1][ks].v, A);
    }
    __syncthreads();
    float* red = (float*)ldsW;
    if (wave >= 2) *(f32x4*)(red + ((wave&1)*64 + lane)*20) = A;
    __syncthreads();
    if (wave < 2){
      A += *(const f32x4*)(red + ((wave&1)*64 + lane)*20);
      #pragma unroll
      for (int rr = 0; rr < 4; ++rr) ccreg[rr] = A[rr] + bcc[rr];
    }
  };

  // ---- out-cell phase (lw 64..83). entry: ch0..3 = Wout ----
  auto phase_out = [&](int t, const u16* hIn){
    f32x4 A0={0,0,0,0}, A1={0,0,0,0}, A2={0,0,0,0}, A3={0,0,0,0};
    const char* hf = (const char*)hIn + (bt << 15) + foff;
    const int ksb = pair << 4;
    int jl = (kg << 2), jjo = ((lw - 64) << 4) + jl;
    FRAG sh[2][8];
    f32x4 bg0, bg1, bg2, bg3;
    // counted issue: hL1(8) hL2(8) bias(4) = 20
    #pragma unroll
    for (int ks = 0; ks < 8; ++ks) ld16sc(sh[0][ks], hf + (ksb + ks)*1024);
    #pragma unroll
    for (int ks = 0; ks < 8; ++ks) ld16sc(sh[1][ks], hf + (ksb + 8 + ks)*1024);
    ldf4(bg0, b_out +       jjo);
    ldf4(bg1, b_out + 320 + jjo);
    ldf4(bg2, b_out + 640 + jjo);
    ldf4(bg3, b_out + 960 + jjo);
    WAITV(12);
    const u16* lbA = ldsW + (pair*2)*16384;
    #pragma unroll
    for (int ks = 0; ks < 8; ++ks){
      int kb = (ks << 6) + (kg << 4);
      FRAG a;
      a.v = afL(lbA, bl, kb);      A0 = MFMA16(a.v, sh[0][ks].v, A0);
      a.v = afL(lbA, 16 + bl, kb); A1 = MFMA16(a.v, sh[0][ks].v, A1);
      a.v = afL(lbA, 32 + bl, kb); A2 = MFMA16(a.v, sh[0][ks].v, A2);
      a.v = afL(lbA, 48 + bl, kb); A3 = MFMA16(a.v, sh[0][ks].v, A3);
    }
    WAITV(4);
    const u16* lbB = ldsW + (pair*2+1)*16384;
    #pragma unroll
    for (int ks = 0; ks < 8; ++ks){
      int kb = (ks << 6) + (kg << 4);
      FRAG a;
      a.v = afL(lbB, bl, kb);      A0 = MFMA16(a.v, sh[1][ks].v, A0);
      a.v = afL(lbB, 16 + bl, kb); A1 = MFMA16(a.v, sh[1][ks].v, A1);
      a.v = afL(lbB, 32 + bl, kb); A2 = MFMA16(a.v, sh[1][ks].v, A2);
      a.v = afL(lbB, 48 + bl, kb); A3 = MFMA16(a.v, sh[1][ks].v, A3);
    }
    __syncthreads();
    float* red = (float*)ldsW;
    if (wave >= 2){
      float* r = red + ((wave&1)*64 + lane)*20;
      *(f32x4*)(r+0) = A0; *(f32x4*)(r+4) = A1;
      *(f32x4*)(r+8) = A2; *(f32x4*)(r+12) = A3;
    }
    __syncthreads();
    if (wave < 2){
      const float* r = red + ((wave&1)*64 + lane)*20;
      A0 += *(const f32x4*)(r+0); A1 += *(const f32x4*)(r+4);
      A2 += *(const f32x4*)(r+8); A3 += *(const f32x4*)(r+12);
      f32x4 ho;
      #pragma unroll
      for (int rr = 0; rr < 4; ++rr){
        float gi = A0[rr] + bg0[rr];
        float gf = A1[rr] + bg1[rr];
        float gg = A2[rr] + bg2[rr];
        float go = A3[rr] + bg3[rr];
        float cn = sigm(gf)*ccreg[rr] + sigm(gi)*tanh_(gg);
        ho[rr] = sigm(go)*tanh_(cn);
      }
      *(f32x4*)(outp + (size_t)b*81920 + (size_t)(t+1)*320 + jjo) = ho;
    }
  };

  // ---- init: cprev from cF (written by k_dense), first incell weights ----
  if (lw < 64){
    if (wave < 2){
      int jj = (lw << 4) + (kg << 2);
      cprev = *(const f32x4*)(cF + (size_t)b*1024 + jj);
    }
    stage1(Win_h + ((size_t)lw << 16) + wave*16384, ldsW + wave*16384, 32);
    stage1(Win_x + (size_t)lw*20480 + wave*4096, ldsW + 65536 + wave*4096, 8);
  }
  __syncthreads();
  SCHEDB();

  u16* hB0 = hS;        u16* hB1 = hS + 65536;
  u16* cB0 = cS;        u16* cB1 = cS + 65536;

  u32 ep = 1;
  if (lw < 64){
    phase_incell(0, hB1, hB0, cB0);
    gs_cell(ep, Wcell + (size_t)lw*81920);
  } else {
    gsync(ep, nullptr, nullptr, 0);
  }
  ++ep;
  int p = 1;
  #pragma unroll 1
  for (int t = 0; t < 255; ++t){
    #pragma unroll 1
    for (int i = 0; i < 4; ++i){
      u16* hIn = (p & 1) ? hB0 : hB1;  u16* cIn = (p & 1) ? cB0 : cB1;
      u16* hOut = (p & 1) ? hB1 : hB0; u16* cOut = (p & 1) ? cB1 : cB0;
      if (lw < 64){
        phase_cell(i, hIn, cIn, hOut, cOut, i == 3);
        if (i < 3) gs_cell(ep, Wcell + (size_t)((i+1)*64 + lw)*81920);
        else       gs_incell(ep);
      } else {
        if (i == 3) phase_ccA(cIn);
        if (i == 2)      gs_ccA(ep);
        else if (i == 3) gs_out(ep);
        else             gsync(ep, nullptr, nullptr, 0);
      }
      ++ep; ++p;
    }
    u16* hIn = (p & 1) ? hB0 : hB1;
    u16* hOut = (p & 1) ? hB1 : hB0; u16* cOut = (p & 1) ? cB1 : cB0;
    if (lw >= 64){
      phase_out(t, hIn);
      gsync(ep, nullptr, nullptr, 0);
    } else {
      if (t < 254){
        phase_incell(t + 1, hIn, hOut, cOut);
        gs_cell(ep, Wcell + (size_t)lw*81920);
      } else {
        gsync(ep, nullptr, nullptr, 0);
      }
    }
    ++ep; ++p;
  }
}

// ---------------------------------------------------------------------------
// Precompute kernels
// ---------------------------------------------------------------------------

__global__ __launch_bounds__(256) void k_dense(const float* __restrict__ X, int xmode,
    const float* __restrict__ W, const float* __restrict__ bias,
    int OD, int ID, int act, int omode, float* outF, u16* outB)
{
  int o = blockIdx.x*4 + (threadIdx.x >> 6);
  if (o >= OD) return;
  int lane = threadIdx.x & 63;
  const float* wr = W + (size_t)o*ID;
  float acc = 0.f;
  if (xmode == 0){ for (int k = 0; k < ID; ++k) acc = fmaf(wr[k], X[(size_t)lane*ID + k], acc); }
  else           { for (int k = 0; k < ID; ++k) acc = fmaf(wr[k], X[(size_t)k*64 + lane], acc); }
  acc += bias[o];
  if (act) acc = acc * sigm(acc);
  if (omode == 0)      outF[(size_t)o*64 + lane] = acc;
  else if (omode == 1){
    int bt = lane >> 4, blx = lane & 15;
    outB[(size_t)bt*16384 + (size_t)(o>>5)*512 + blx*32 + ((o&31)>>3)*8 + (o&7)] = f2bf(acc);
  }
  else if (omode == 2) outF[(size_t)lane*1024 + o] = acc;
  else                 outF[(size_t)lane*81920 + 256 + o] = acc;
}

__global__ void k_zero0(float* out){ out[(size_t)blockIdx.x*81920 + threadIdx.x] = 0.f; }

// f32 -> bf16 flat convert (4 elems/thread). Grid MUST be N/(256*4) blocks.
__global__ void k_cvt(const float* __restrict__ src, u16* __restrict__ dst){
  int id = (blockIdx.x*256 + threadIdx.x)*4;
  f32x4 v = *(const f32x4*)(src + id);
  P4 o; o.s[0]=f2bf(v[0]); o.s[1]=f2bf(v[1]); o.s[2]=f2bf(v[2]); o.s[3]=f2bf(v[3]);
  *(u64*)(dst + id) = o.q;
}

__global__ __launch_bounds__(256) void k_tr(const float* __restrict__ in, u16* __restrict__ out, int M, int N){
  __shared__ u16 t[64][65];
  int m0 = blockIdx.x << 6, n0 = blockIdx.y << 6;
  int c = threadIdx.x & 63, rq = threadIdx.x >> 6;
  for (int rr = 0; rr < 16; ++rr){
    int r = (rq << 4) + rr;
    t[r][c] = f2bf(in[(size_t)(m0 + r)*N + n0 + c]);
  }
  __syncthreads();
  for (int rr = 0; rr < 16; ++rr){
    int r = (rq << 4) + rr;
    out[(size_t)(n0 + r)*M + m0 + c] = t[c][r];
  }
}

__global__ __launch_bounds__(256) void k_fuse(const float* __restrict__ Whh,
    const u16* __restrict__ Abf, const float* __restrict__ Wih,
    const u16* __restrict__ BT, int KM, int mode, u16* __restrict__ dst)
{
  int bx = blockIdx.x, by = blockIdx.y, bz = blockIdx.z;
  int lane = threadIdx.x & 63, wv = threadIdx.x >> 6;
  int bl = lane & 15, kg = lane >> 4;
  int jbase = (mode == 0) ? bz*1024 : ((mode == 1) ? bz*320 : 0);
  int jrow = jbase + bx*16 + bl;
  int k2c = by*64 + wv*16 + bl;
  f32x4 acc = {0,0,0,0};
  for (int m0 = 0; m0 < KM; m0 += 32){
    FRAG a;
    if (Abf){
      a.v = *(const bf16x8*)(Abf + (size_t)jrow*KM + m0 + (kg << 3));
    } else {
      f32x4 wa0 = *(const f32x4*)(Whh + (size_t)jrow*KM + m0 + (kg << 3));
      f32x4 wa1 = *(const f32x4*)(Whh + (size_t)jrow*KM + m0 + (kg << 3) + 4);
      a.s[0]=f2bf(wa0[0]); a.s[1]=f2bf(wa0[1]); a.s[2]=f2bf(wa0[2]); a.s[3]=f2bf(wa0[3]);
      a.s[4]=f2bf(wa1[0]); a.s[5]=f2bf(wa1[1]); a.s[6]=f2bf(wa1[2]); a.s[7]=f2bf(wa1[3]);
    }
    FRAG bb; bb.v = *(const bf16x8*)(BT + (size_t)k2c*KM + m0 + (kg << 3));
    acc = MFMA16(a.v, bb.v, acc);
  }
  #pragma unroll
  for (int r = 0; r < 4; ++r){
    int jl = (kg << 2) + r;
    int jg = jbase + bx*16 + jl;
    float v = acc[r];
    if (mode < 2) v += Wih[(size_t)jg*1024 + k2c];
    int re = (mode == 2) ? jl : (bz*16 + jl);
    int c = k2c >> 8, kl = k2c & 255;
    size_t pos;
    if (mode == 0)      pos = (size_t)bx*81920 + c*20480 + re*256 + (kl ^ ((re&7)<<3));
    else if (mode == 1) pos = (size_t)bx*65536 + c*16384 + re*256 + (kl ^ ((re&7)<<3));
    else                pos = (size_t)bx*16384 + c*4096  + re*256 + (kl ^ ((re&7)<<3));
    dst[pos] = f2bf(v);
  }
}

__global__ void k_pack_winh(const float* __restrict__ src, u16* __restrict__ dst){
  int id = blockIdx.x*256 + threadIdx.x;
  int j = id >> 10, k = id & 1023;
  int g = j >> 10, jj = j & 1023;
  int w = jj >> 4, r = (g << 4) + (jj & 15);
  int c = k >> 8, kl = k & 255;
  dst[(size_t)w*65536 + c*16384 + r*256 + (kl ^ ((r&7)<<3))] = f2bf(src[id]);
}

__global__ void k_pack_winx(const float* __restrict__ src, u16* __restrict__ dst){
  int j = blockIdx.x, k = threadIdx.x;
  int g = j >> 10, jj = j & 1023;
  int w = jj >> 4, r = (g << 4) + (jj & 15);
  float v = src[(size_t)j*320 + k];
  size_t pos;
  if (k < 256) pos = (size_t)w*20480 + r*256 + (k ^ ((r&7)<<3));
  else         pos = (size_t)w*20480 + 16384 + r*64 + ((k - 256) ^ ((r&7)<<3));
  dst[pos] = f2bf(v);
}

__global__ void k_pack_ca(const float* __restrict__ src, u16* __restrict__ dst){
  int id = blockIdx.x*256 + threadIdx.x;
  int jj = id >> 10, k = id & 1023;
  int w = jj >> 4, r = 64 + (jj & 15);
  int c = k >> 8, kl = k & 255;
  dst[(size_t)w*81920 + c*20480 + r*256 + (kl ^ ((r&7)<<3))] = f2bf(src[id]);
}

__global__ __launch_bounds__(256) void k_bias(const float* __restrict__ A, const float* __restrict__ x,
    const float* __restrict__ a1, const float* __restrict__ a2, float* __restrict__ o, int NJ, int K)
{
  int j = blockIdx.x*4 + (threadIdx.x >> 6);
  if (j >= NJ) return;
  int lane = threadIdx.x & 63;
  float acc = 0.f;
  if (A) for (int k = lane; k < K; k += 64) acc += A[(size_t)j*K + k]*x[k];
  for (int off = 32; off; off >>= 1) acc += __shfl_down(acc, off);
  if (lane == 0) o[j] = acc + (a1 ? a1[j] : 0.f) + (a2 ? a2[j] : 0.f);
}

// ---------------------------------------------------------------------------
extern "C" void kernel_launch(void* const* d_in, const int* in_sizes, int n_in,
                              void* d_out, int out_size, void* d_ws, size_t ws_size,
                              hipStream_t stream)
{
  (void)in_sizes; (void)n_in; (void)out_size;
  const float* z      = (const float*)d_in[0];
  const float* m_true = (const float*)d_in[1];
  const float* eh_W1=(const float*)d_in[2],  *eh_b1=(const float*)d_in[3];
  const float* eh_W2=(const float*)d_in[4],  *eh_b2=(const float*)d_in[5];
  const float* eh_W3=(const float*)d_in[6],  *eh_b3=(const float*)d_in[7];
  const float* ec_W1=(const float*)d_in[8],  *ec_b1=(const float*)d_in[9];
  const float* ec_W2=(const float*)d_in[10], *ec_b2=(const float*)d_in[11];
  const float* ec_W3=(const float*)d_in[12], *ec_b3=(const float*)d_in[13];
  const float* ex_W1=(const float*)d_in[14], *ex_b1=(const float*)d_in[15];
  const float* ex_W2=(const float*)d_in[16], *ex_b2=(const float*)d_in[17];
  const float* ex_W3=(const float*)d_in[18], *ex_b3=(const float*)d_in[19];
  const float* in_Wih=(const float*)d_in[20], *in_Whh=(const float*)d_in[21];
  const float* in_bih=(const float*)d_in[22], *in_bhh=(const float*)d_in[23];
  const float* r_Wih=(const float*)d_in[24],  *r_Whh=(const float*)d_in[25];
  const float* r_bih=(const float*)d_in[26],  *r_bhh=(const float*)d_in[27];
  const float* hA_W=(const float*)d_in[28],   *hA_b=(const float*)d_in[29];
  const float* cA_W=(const float*)d_in[30],   *cA_b=(const float*)d_in[31];
  const float* lastH_W=(const float*)d_in[32], *lastH_b=(const float*)d_in[33];
  const float* lastC_W=(const float*)d_in[34], *lastC_b=(const float*)d_in[35];
  const float* out_Wih=(const float*)d_in[36], *out_Whh=(const float*)d_in[37];
  const float* out_bih=(const float*)d_in[38], *out_bhh=(const float*)d_in[39];
  float* out = (float*)d_out;

  char* wsb = (char*)d_ws;
  size_t off = 0;
  auto alloc = [&](size_t bytes)->char*{
    char* p = wsb + off; off = (off + bytes + 255) & ~(size_t)255; return p;
  };
  u32* bar    = (u32*)alloc(256*32*4);
  u16* hS     = (u16*)alloc(2*64*1024*2);
  u16* cS     = (u16*)alloc(2*64*1024*2);
  float* cF   = (float*)alloc(64*1024*4);
  float* b_in = (float*)alloc(4096*4);
  float* b_cell=(float*)alloc(4*4096*4);
  float* b_out= (float*)alloc(1280*4);
  float* b_cc = (float*)alloc(320*4);
  float* t1   = (float*)alloc(1024*64*4);
  float* t2   = (float*)alloc(1024*64*4);
  u16* Tbuf   = (u16*)alloc((size_t)1024*1024*2);
  u16* Wbf    = (u16*)alloc((size_t)4096*1024*2);
  u16* Win_h  = (u16*)alloc((size_t)64*65536*2);
  u16* Win_x  = (u16*)alloc((size_t)64*20480*2);
  u16* Wcell  = (u16*)alloc((size_t)4*64*81920*2);
  u16* Wout   = (u16*)alloc((size_t)20*65536*2);
  u16* WccA   = (u16*)alloc((size_t)20*16384*2);
  if (off > ws_size) return;

  hipMemsetAsync(bar, 0, 256*32*4, stream);

  k_dense<<<256,256,0,stream>>>(z, 0, eh_W1, eh_b1, 1024, 256, 1, 0, t1, nullptr);
  k_dense<<<256,256,0,stream>>>(t1,1, eh_W2, eh_b2, 1024,1024, 1, 0, t2, nullptr);
  k_dense<<<256,256,0,stream>>>(t2,1, eh_W3, eh_b3, 1024,1024, 0, 1, nullptr, hS + 65536);
  k_dense<<<256,256,0,stream>>>(z, 0, ec_W1, ec_b1, 1024, 256, 1, 0, t1, nullptr);
  k_dense<<<256,256,0,stream>>>(t1,1, ec_W2, ec_b2, 1024,1024, 1, 0, t2, nullptr);
  k_dense<<<256,256,0,stream>>>(t2,1, ec_W3, ec_b3, 1024,1024, 0, 2, cF, nullptr);
  k_dense<<<256,256,0,stream>>>(z, 0, ex_W1, ex_b1, 1024, 256, 1, 0, t1, nullptr);
  k_dense<<<256,256,0,stream>>>(t1,1, ex_W2, ex_b2, 1024,1024, 1, 0, t2, nullptr);
  k_dense<<<16 ,256,0,stream>>>(t2,1, ex_W3, ex_b3,   64,1024, 0, 3, out, nullptr);
  k_zero0<<<64,256,0,stream>>>(out);

  k_pack_winh<<<16384,256,0,stream>>>(in_Whh, Win_h);
  k_pack_winx<<<4096,320,0,stream>>>(in_Wih, Win_x);
  for (int i = 0; i < 4; ++i)
    k_pack_ca<<<4096,256,0,stream>>>(cA_W + (size_t)i*1024*1024, Wcell + (size_t)i*64*81920);

  for (int i = 0; i < 4; ++i){
    // 4096*1024 elems / (256 thr * 4 elems) = 4096 blocks
    k_cvt<<<4096,256,0,stream>>>(r_Whh + (size_t)i*4096*1024, Wbf);
    k_tr<<<dim3(16,16),256,0,stream>>>(hA_W + (size_t)i*1024*1024, Tbuf, 1024, 1024);
    k_fuse<<<dim3(64,16,4),256,0,stream>>>(r_Whh + (size_t)i*4096*1024, Wbf,
                                           r_Wih + (size_t)i*4096*1024,
                                           Tbuf, 1024, 0, Wcell + (size_t)i*64*81920);
  }
  k_tr<<<dim3(5,16),256,0,stream>>>(lastH_W, Tbuf, 320, 1024);
  k_fuse<<<dim3(20,16,4),256,0,stream>>>(out_Whh, nullptr, out_Wih, Tbuf, 320, 1, Wout);
  k_tr<<<dim3(16,16),256,0,stream>>>(cA_W + (size_t)3*1024*1024, Tbuf, 1024, 1024);
  k_fuse<<<dim3(20,16,1),256,0,stream>>>(lastC_W, nullptr, nullptr, Tbuf, 1024, 2, WccA);

  k_bias<<<1024,256,0,stream>>>(nullptr, nullptr, in_bih, in_bhh, b_in, 4096, 0);
  for (int i = 0; i < 4; ++i)
    k_bias<<<1024,256,0,stream>>>(r_Whh + (size_t)i*4096*1024, hA_b + i*1024,
                                  r_bih + i*4096, r_bhh + i*4096, b_cell + i*4096, 4096, 1024);
  k_bias<<<320,256,0,stream>>>(out_Whh, lastH_b, out_bih, out_bhh, b_out, 1280, 320);
  k_bias<<<80 ,256,0,stream>>>(lastC_W, cA_b + 3*1024, lastC_b, nullptr, b_cc, 320, 1024);

  k_scan<<<NWG,256,0,stream>>>(m_true, Wcell, Win_h, Win_x, Wout, WccA,
                               b_in, b_cell, cA_b, b_out, b_cc,
                               hS, cS, cF, out, bar);
}

// Round 12
// 11583.401 us; speedup vs baseline: 1.3217x; 1.0688x over previous
//
#include <hip/hip_runtime.h>

// BigARDecoder: persistent-kernel LSTM scan on MI355X.
// B=64, T=256, IN=256, H=1024, G=256, O=64, D=4, GO=320.
//
// R12 = R8 scan VERBATIM (best measured: 9.65ms) + precompute overhaul:
// - k_fuse tiles 64 j-rows per block (4 accumulators share one B-fragment)
//   -> B-operand traffic /4 (was the dominant precompute cost),
// - A-operand pre-converted to bf16 (k_cvt, grid fixed at 4096 blocks).
// R11's wave-0-poll-only staging split REVERTED (it lengthened the per-wave
// staging critical path 40->54 segs and cost 0.75us/phase).

typedef unsigned int u32;
typedef unsigned long long u64;
typedef unsigned short u16;
typedef __attribute__((ext_vector_type(8))) __bf16 bf16x8;
typedef __attribute__((ext_vector_type(4))) float f32x4;

#define DEVI __device__ __forceinline__

union FRAG { bf16x8 v; u16 s[8]; u64 q[2]; };
union P4 { u64 q; u16 s[4]; };
union F4 { u64 q[2]; float f[4]; };

DEVI u16 f2bf(float x){ u32 u = __float_as_uint(x); return (u16)((u + 0x7fffu + ((u>>16)&1u)) >> 16); }
DEVI float sigm(float x){ return 1.0f/(1.0f + __expf(-x)); }
DEVI float tanh_(float x){ return 2.0f/(1.0f + __expf(-2.0f*x)) - 1.0f; }
DEVI void ast(void* p, u64 v){ __hip_atomic_store((u64*)p, v, __ATOMIC_RELAXED, __HIP_MEMORY_SCOPE_AGENT); }

// counted asm loads (issue order == program order of volatiles == vmcnt FIFO)
DEVI void ld16sc(FRAG& d, const void* p){
  asm volatile("global_load_dwordx4 %0, %1, off sc0 sc1" : "=v"(d.v) : "v"(p));
}
DEVI void ld16(FRAG& d, const void* p){
  asm volatile("global_load_dwordx4 %0, %1, off" : "=v"(d.v) : "v"(p));
}
DEVI void ldf4(f32x4& d, const void* p){
  asm volatile("global_load_dwordx4 %0, %1, off" : "=v"(d) : "v"(p));
}

#define MFMA16(a,b,c) __builtin_amdgcn_mfma_f32_16x16x32_bf16(a, b, c, 0, 0, 0)

#define NWG 168

#define SCHEDB() __builtin_amdgcn_sched_barrier(0)
#define WAITV(n) do{ SCHEDB(); \
  asm volatile("s_waitcnt vmcnt(" #n ")" ::: "memory"); \
  SCHEDB(); }while(0)

// ---------------------------------------------------------------------------
// Persistent scan kernel. 168 WGs x 256 threads (no master).
// wg -> (pipe, lw): twins 8 apart (same XCD). lw 0..63: hidden tiles;
// lw 64..83: out-cell / ccA tiles. Wave w = (pair=w>>1 K-half, bt=(pipe<<1)+(w&1)).
// State frag layout (per buffer, 128KB): [btile(4)][ks(32)][bl(16)][kg(4)][8 bf16]
// LDS: 160KB weight chunks. Flags: bar + (pipe*128 + lw)*32 (128B lines).
// ---------------------------------------------------------------------------
__global__ __launch_bounds__(256, 1) void k_scan(
    const float* __restrict__ m_true,
    const u16* __restrict__ Wcell, const u16* __restrict__ Win_h,
    const u16* __restrict__ Win_x, const u16* __restrict__ Wout,
    const u16* __restrict__ WccA,
    const float* __restrict__ b_in, const float* __restrict__ b_cell,
    const float* __restrict__ cAb, const float* __restrict__ b_out,
    const float* __restrict__ b_cc,
    u16* hS, u16* cS, float* cF, float* outp, u32* bar)
{
  const int wg = blockIdx.x;
  const int tid = threadIdx.x;
  const int wave = tid >> 6, lane = tid & 63;

  int pipe, lw;
  if (wg < 160){ pipe = (wg >> 3) & 1; lw = ((wg >> 4) << 3) | (wg & 7); }
  else         { pipe = (wg - 160) >> 2; lw = 80 + ((wg - 160) & 3); }

  const int bl = lane & 15, kg = lane >> 4;
  const int pair = wave >> 1;               // K-half this wave owns
  const int bt = (pipe << 1) + (wave & 1);  // btile this wave owns
  const int b  = (bt << 4) + bl;
  const int swz = (bl & 7) << 4;
  const int foff = ((bl << 2) + kg) << 4;
  const int woff = (bt << 15) + ((lw >> 1) << 10) + (bl << 6) + ((lw & 1) << 5) + (kg << 3);
  u32* flagp = bar + (pipe*128 + lw)*32;
  const u32* fbase = bar + pipe*128*32;
  const int i2 = (lane < 20) ? 64 + lane : lane;   // poll coverage 0..83
  __shared__ __align__(16) u16 ldsW[81920];   // 160KB weight chunks

  f32x4 cprev = {0,0,0,0};   // cell WGs (wave<2): c carry cell3 -> in-cell
  f32x4 ccreg = {0,0,0,0};   // out  WGs (wave<2): cc carry ccA -> out

  auto stage1 = [&](const u16* src, u16* lb, int segs){
    const u16* g = src + (lane << 3);
    u16* l = lb;
    for (int s = 0; s < segs; ++s){
      __builtin_amdgcn_global_load_lds(
          (const __attribute__((address_space(1))) void*)g,
          (__attribute__((address_space(3))) void*)l, 16, 0, 0);
      g += 512; l += 512;
    }
    SCHEDB();
  };
  auto afL = [&](const u16* lb, int row, int kb) -> bf16x8 {
    return *(const bf16x8*)((const char*)lb + row*512 + (kb ^ swz));
  };

  // masterless barrier: flag bump; each wave stages its own next-phase chunk;
  // wave 0 polls all 84 flags of this pipeline directly.
  auto gsync = [&](u32 ep, const u16* pfsrc, int cstride, int spw, const u16* xsrc){
    SCHEDB();
    __syncthreads();                  // per-wave vmcnt(0): state stores acked
    if (tid == 0)
      __hip_atomic_store(flagp, ep, __ATOMIC_RELAXED, __HIP_MEMORY_SCOPE_AGENT);
    SCHEDB();
    if (pfsrc) stage1(pfsrc + (size_t)wave*cstride, ldsW + wave*cstride, spw);
    if (xsrc)  stage1(xsrc + wave*4096, ldsW + 65536 + wave*4096, 8);
    SCHEDB();
    if (wave == 0){
      for(;;){
        u32 a = __hip_atomic_load(fbase + lane*32, __ATOMIC_RELAXED, __HIP_MEMORY_SCOPE_AGENT);
        u32 c2 = __hip_atomic_load(fbase + i2*32, __ATOMIC_RELAXED, __HIP_MEMORY_SCOPE_AGENT);
        if (__all(a >= ep && c2 >= ep)) break;
        __builtin_amdgcn_s_sleep(1);
      }
    }
    __syncthreads();                  // broadcast + drain weight stage
    SCHEDB();
  };

  // ---- in-cell phase (lw<64). entry: ch0..3 = Win_h, ch4 = Win_x part1 ----
  auto phase_incell = [&](int t, const u16* hIn, u16* hOut, u16* cOut){
    f32x4 A0={0,0,0,0}, A1={0,0,0,0}, A2={0,0,0,0}, A3={0,0,0,0};
    const char* hf = (const char*)hIn + (bt << 15) + foff;
    const int ksb = pair << 4;
    int jl = (kg << 2), jj = (lw << 4) + jl;
    FRAG sh[2][8], pa[8];
    f32x4 bg0, bg1, bg2, bg3;
    // counted issue: hL1(8) hL2(8) pa(8) bias(4) = 28
    #pragma unroll
    for (int ks = 0; ks < 8; ++ks) ld16sc(sh[0][ks], hf + (ksb + ks)*1024);
    #pragma unroll
    for (int ks = 0; ks < 8; ++ks) ld16sc(sh[1][ks], hf + (ksb + 8 + ks)*1024);
    {
      const char* p2 = (const char*)(Win_x + (size_t)lw*20480 + 16384);
      #pragma unroll
      for (int k2 = 0; k2 < 2; ++k2)
        #pragma unroll
        for (int rb = 0; rb < 4; ++rb)
          ld16(pa[k2*4+rb], p2 + (rb*16 + bl)*128 + (((k2<<6)+(kg<<4)) ^ swz));
    }
    ldf4(bg0, b_in +        jj);
    ldf4(bg1, b_in + 1024 + jj);
    ldf4(bg2, b_in + 2048 + jj);
    ldf4(bg3, b_in + 3072 + jj);
    WAITV(20);
    const u16* lbA = ldsW + (pair*2)*16384;
    #pragma unroll
    for (int ks = 0; ks < 8; ++ks){
      int kb = (ks << 6) + (kg << 4);
      FRAG a;
      a.v = afL(lbA, bl, kb);      A0 = MFMA16(a.v, sh[0][ks].v, A0);
      a.v = afL(lbA, 16 + bl, kb); A1 = MFMA16(a.v, sh[0][ks].v, A1);
      a.v = afL(lbA, 32 + bl, kb); A2 = MFMA16(a.v, sh[0][ks].v, A2);
      a.v = afL(lbA, 48 + bl, kb); A3 = MFMA16(a.v, sh[0][ks].v, A3);
    }
    WAITV(12);
    const u16* lbB = ldsW + (pair*2+1)*16384;
    #pragma unroll
    for (int ks = 0; ks < 8; ++ks){
      int kb = (ks << 6) + (kg << 4);
      FRAG a;
      a.v = afL(lbB, bl, kb);      A0 = MFMA16(a.v, sh[1][ks].v, A0);
      a.v = afL(lbB, 16 + bl, kb); A1 = MFMA16(a.v, sh[1][ks].v, A1);
      a.v = afL(lbB, 32 + bl, kb); A2 = MFMA16(a.v, sh[1][ks].v, A2);
      a.v = afL(lbB, 48 + bl, kb); A3 = MFMA16(a.v, sh[1][ks].v, A3);
    }
    WAITV(4);                               // pa landed (bias outstanding)
    if (wave >= 2){                         // x contribution (pair B only)
      FRAG xf[10];
      const float* xr = m_true + (size_t)b*81920 + (size_t)(255 - t)*320;
      #pragma unroll
      for (int ks = 0; ks < 10; ++ks){
        int k = (ks << 5) + (kg << 3);
        f32x4 x0 = *(const f32x4*)(xr + k);
        f32x4 x1 = *(const f32x4*)(xr + k + 4);
        xf[ks].s[0]=f2bf(x0[0]); xf[ks].s[1]=f2bf(x0[1]); xf[ks].s[2]=f2bf(x0[2]); xf[ks].s[3]=f2bf(x0[3]);
        xf[ks].s[4]=f2bf(x1[0]); xf[ks].s[5]=f2bf(x1[1]); xf[ks].s[6]=f2bf(x1[2]); xf[ks].s[7]=f2bf(x1[3]);
      }
      const u16* lb4 = ldsW + 65536;
      #pragma unroll
      for (int ks = 0; ks < 8; ++ks){
        int kb = (ks << 6) + (kg << 4);
        FRAG a;
        a.v = afL(lb4, bl, kb);      A0 = MFMA16(a.v, xf[ks].v, A0);
        a.v = afL(lb4, 16 + bl, kb); A1 = MFMA16(a.v, xf[ks].v, A1);
        a.v = afL(lb4, 32 + bl, kb); A2 = MFMA16(a.v, xf[ks].v, A2);
        a.v = afL(lb4, 48 + bl, kb); A3 = MFMA16(a.v, xf[ks].v, A3);
      }
      #pragma unroll
      for (int k2 = 0; k2 < 2; ++k2){
        A0 = MFMA16(pa[k2*4+0].v, xf[8+k2].v, A0);
        A1 = MFMA16(pa[k2*4+1].v, xf[8+k2].v, A1);
        A2 = MFMA16(pa[k2*4+2].v, xf[8+k2].v, A2);
        A3 = MFMA16(pa[k2*4+3].v, xf[8+k2].v, A3);
      }
    }
    __syncthreads();                        // also drains bias/xf
    float* red = (float*)ldsW;
    if (wave >= 2){
      float* r = red + ((wave&1)*64 + lane)*20;
      *(f32x4*)(r+0) = A0; *(f32x4*)(r+4) = A1;
      *(f32x4*)(r+8) = A2; *(f32x4*)(r+12) = A3;
    }
    __syncthreads();
    if (wave < 2){
      const float* r = red + ((wave&1)*64 + lane)*20;
      A0 += *(const f32x4*)(r+0); A1 += *(const f32x4*)(r+4);
      A2 += *(const f32x4*)(r+8); A3 += *(const f32x4*)(r+12);
      P4 hw, cw;
      #pragma unroll
      for (int rr = 0; rr < 4; ++rr){
        float gi = A0[rr] + bg0[rr];
        float gf = A1[rr] + bg1[rr];
        float gg = A2[rr] + bg2[rr];
        float go = A3[rr] + bg3[rr];
        float cn = sigm(gf)*cprev[rr] + sigm(gi)*tanh_(gg);
        hw.s[rr] = f2bf(sigm(go)*tanh_(cn));
        cw.s[rr] = f2bf(cn);
      }
      ast((char*)hOut + woff, hw.q);
      ast((char*)cOut + woff, cw.q);
    }
  };

  // ---- inner cell phase i (lw<64). entry: ch0..3 = Wcell_i ----
  auto phase_cell = [&](int i, const u16* hIn, const u16* cIn, u16* hOut, u16* cOut, bool last){
    f32x4 A0={0,0,0,0}, A1={0,0,0,0}, A2={0,0,0,0}, A3={0,0,0,0}, A4={0,0,0,0};
    const char* hf  = (const char*)hIn + (bt << 15) + foff;
    const char* cfr = (const char*)cIn + (bt << 15) + foff;
    const int ksb = pair << 4;
    int jl = (kg << 2), jj = (lw << 4) + jl;
    FRAG sh[2][8], sc[2][8];
    f32x4 bg0, bg1, bg2, bg3, bca;
    // counted issue: hL1(8) cL1(8) hL2(8) cL2(8) bias(5) = 37
    #pragma unroll
    for (int ks = 0; ks < 8; ++ks) ld16sc(sh[0][ks], hf  + (ksb + ks)*1024);
    #pragma unroll
    for (int ks = 0; ks < 8; ++ks) ld16sc(sc[0][ks], cfr + (ksb + ks)*1024);
    #pragma unroll
    for (int ks = 0; ks < 8; ++ks) ld16sc(sh[1][ks], hf  + (ksb + 8 + ks)*1024);
    #pragma unroll
    for (int ks = 0; ks < 8; ++ks) ld16sc(sc[1][ks], cfr + (ksb + 8 + ks)*1024);
    ldf4(bg0, b_cell + i*4096 +        jj);
    ldf4(bg1, b_cell + i*4096 + 1024 + jj);
    ldf4(bg2, b_cell + i*4096 + 2048 + jj);
    ldf4(bg3, b_cell + i*4096 + 3072 + jj);
    ldf4(bca, cAb + i*1024 + jj);
    WAITV(21);
    const u16* lbA = ldsW + (pair*2)*20480;
    #pragma unroll
    for (int ks = 0; ks < 8; ++ks){
      int kb = (ks << 6) + (kg << 4);
      FRAG a;
      a.v = afL(lbA, bl, kb);      A0 = MFMA16(a.v, sh[0][ks].v, A0);
      a.v = afL(lbA, 16 + bl, kb); A1 = MFMA16(a.v, sh[0][ks].v, A1);
      a.v = afL(lbA, 32 + bl, kb); A2 = MFMA16(a.v, sh[0][ks].v, A2);
      a.v = afL(lbA, 48 + bl, kb); A3 = MFMA16(a.v, sh[0][ks].v, A3);
      a.v = afL(lbA, 64 + bl, kb); A4 = MFMA16(a.v, sc[0][ks].v, A4);
    }
    WAITV(5);
    const u16* lbB = ldsW + (pair*2+1)*20480;
    #pragma unroll
    for (int ks = 0; ks < 8; ++ks){
      int kb = (ks << 6) + (kg << 4);
      FRAG a;
      a.v = afL(lbB, bl, kb);      A0 = MFMA16(a.v, sh[1][ks].v, A0);
      a.v = afL(lbB, 16 + bl, kb); A1 = MFMA16(a.v, sh[1][ks].v, A1);
      a.v = afL(lbB, 32 + bl, kb); A2 = MFMA16(a.v, sh[1][ks].v, A2);
      a.v = afL(lbB, 48 + bl, kb); A3 = MFMA16(a.v, sh[1][ks].v, A3);
      a.v = afL(lbB, 64 + bl, kb); A4 = MFMA16(a.v, sc[1][ks].v, A4);
    }
    __syncthreads();
    float* red = (float*)ldsW;
    if (wave >= 2){
      float* r = red + ((wave&1)*64 + lane)*20;
      *(f32x4*)(r+0) = A0; *(f32x4*)(r+4) = A1;
      *(f32x4*)(r+8) = A2; *(f32x4*)(r+12) = A3; *(f32x4*)(r+16) = A4;
    }
    __syncthreads();
    if (wave < 2){
      const float* r = red + ((wave&1)*64 + lane)*20;
      A0 += *(const f32x4*)(r+0); A1 += *(const f32x4*)(r+4);
      A2 += *(const f32x4*)(r+8); A3 += *(const f32x4*)(r+12);
      A4 += *(const f32x4*)(r+16);
      P4 hw, cw; F4 cf4;
      #pragma unroll
      for (int rr = 0; rr < 4; ++rr){
        float gi = A0[rr] + bg0[rr];
        float gf = A1[rr] + bg1[rr];
        float gg = A2[rr] + bg2[rr];
        float go = A3[rr] + bg3[rr];
        float c1 = A4[rr] + bca[rr];
        float cn = sigm(gf)*c1 + sigm(gi)*tanh_(gg);
        hw.s[rr] = f2bf(sigm(go)*tanh_(cn));
        cw.s[rr] = f2bf(cn);
        cf4.f[rr] = cn;
      }
      ast((char*)hOut + woff, hw.q);
      ast((char*)cOut + woff, cw.q);
      if (last){ cprev[0]=cf4.f[0]; cprev[1]=cf4.f[1]; cprev[2]=cf4.f[2]; cprev[3]=cf4.f[3]; }
    }
  };

  // ---- ccA phase (lw 64..83, with cell i==3). entry: ch0..3 = WccA ----
  auto phase_ccA = [&](const u16* cIn){
    f32x4 A = {0,0,0,0};
    const char* cfr = (const char*)cIn + (bt << 15) + foff;
    const int ksb = pair << 4;
    int jl = (kg << 2), jjo = ((lw - 64) << 4) + jl;
    FRAG sc[2][8];
    f32x4 bcc;
    // counted issue: cL1(8) cL2(8) bcc(1) = 17
    #pragma unroll
    for (int ks = 0; ks < 8; ++ks) ld16sc(sc[0][ks], cfr + (ksb + ks)*1024);
    #pragma unroll
    for (int ks = 0; ks < 8; ++ks) ld16sc(sc[1][ks], cfr + (ksb + 8 + ks)*1024);
    ldf4(bcc, b_cc + jjo);
    WAITV(9);
    const u16* lbA = ldsW + (pair*2)*4096;
    #pragma unroll
    for (int ks = 0; ks < 8; ++ks){
      int kb = (ks << 6) + (kg << 4);
      FRAG a; a.v = afL(lbA, bl, kb);
      A = MFMA16(a.v, sc[0][ks].v, A);
    }
    WAITV(1);
    const u16* lbB = ldsW + (pair*2+1)*4096;
    #pragma unroll
    for (int ks = 0; ks < 8; ++ks){
      int kb = (ks << 6) + (kg << 4);
      FRAG a; a.v = afL(lbB, bl, kb);
      A = MFMA16(a.v, sc[1][ks].v, A);
    }
    __syncthreads();
    float* red = (float*)ldsW;
    if (wave >= 2) *(f32x4*)(red + ((wave&1)*64 + lane)*20) = A;
    __syncthreads();
    if (wave < 2){
      A += *(const f32x4*)(red + ((wave&1)*64 + lane)*20);
      #pragma unroll
      for (int rr = 0; rr < 4; ++rr) ccreg[rr] = A[rr] + bcc[rr];
    }
  };

  // ---- out-cell phase (lw 64..83). entry: ch0..3 = Wout ----
  auto phase_out = [&](int t, const u16* hIn){
    f32x4 A0={0,0,0,0}, A1={0,0,0,0}, A2={0,0,0,0}, A3={0,0,0,0};
    const char* hf = (const char*)hIn + (bt << 15) + foff;
    const int ksb = pair << 4;
    int jl = (kg << 2), jjo = ((lw - 64) << 4) + jl;
    FRAG sh[2][8];
    f32x4 bg0, bg1, bg2, bg3;
    // counted issue: hL1(8) hL2(8) bias(4) = 20
    #pragma unroll
    for (int ks = 0; ks < 8; ++ks) ld16sc(sh[0][ks], hf + (ksb + ks)*1024);
    #pragma unroll
    for (int ks = 0; ks < 8; ++ks) ld16sc(sh[1][ks], hf + (ksb + 8 + ks)*1024);
    ldf4(bg0, b_out +       jjo);
    ldf4(bg1, b_out + 320 + jjo);
    ldf4(bg2, b_out + 640 + jjo);
    ldf4(bg3, b_out + 960 + jjo);
    WAITV(12);
    const u16* lbA = ldsW + (pair*2)*16384;
    #pragma unroll
    for (int ks = 0; ks < 8; ++ks){
      int kb = (ks << 6) + (kg << 4);
      FRAG a;
      a.v = afL(lbA, bl, kb);      A0 = MFMA16(a.v, sh[0][ks].v, A0);
      a.v = afL(lbA, 16 + bl, kb); A1 = MFMA16(a.v, sh[0][ks].v, A1);
      a.v = afL(lbA, 32 + bl, kb); A2 = MFMA16(a.v, sh[0][ks].v, A2);
      a.v = afL(lbA, 48 + bl, kb); A3 = MFMA16(a.v, sh[0][ks].v, A3);
    }
    WAITV(4);
    const u16* lbB = ldsW + (pair*2+1)*16384;
    #pragma unroll
    for (int ks = 0; ks < 8; ++ks){
      int kb = (ks << 6) + (kg << 4);
      FRAG a;
      a.v = afL(lbB, bl, kb);      A0 = MFMA16(a.v, sh[1][ks].v, A0);
      a.v = afL(lbB, 16 + bl, kb); A1 = MFMA16(a.v, sh[1][ks].v, A1);
      a.v = afL(lbB, 32 + bl, kb); A2 = MFMA16(a.v, sh[1][ks].v, A2);
      a.v = afL(lbB, 48 + bl, kb); A3 = MFMA16(a.v, sh[1][ks].v, A3);
    }
    __syncthreads();
    float* red = (float*)ldsW;
    if (wave >= 2){
      float* r = red + ((wave&1)*64 + lane)*20;
      *(f32x4*)(r+0) = A0; *(f32x4*)(r+4) = A1;
      *(f32x4*)(r+8) = A2; *(f32x4*)(r+12) = A3;
    }
    __syncthreads();
    if (wave < 2){
      const float* r = red + ((wave&1)*64 + lane)*20;
      A0 += *(const f32x4*)(r+0); A1 += *(const f32x4*)(r+4);
      A2 += *(const f32x4*)(r+8); A3 += *(const f32x4*)(r+12);
      f32x4 ho;
      #pragma unroll
      for (int rr = 0; rr < 4; ++rr){
        float gi = A0[rr] + bg0[rr];
        float gf = A1[rr] + bg1[rr];
        float gg = A2[rr] + bg2[rr];
        float go = A3[rr] + bg3[rr];
        float cn = sigm(gf)*ccreg[rr] + sigm(gi)*tanh_(gg);
        ho[rr] = sigm(go)*tanh_(cn);
      }
      *(f32x4*)(outp + (size_t)b*81920 + (size_t)(t+1)*320 + jjo) = ho;
    }
  };

  // ---- init: cprev from cF (written by k_dense), first incell weights ----
  if (lw < 64){
    if (wave < 2){
      int jj = (lw << 4) + (kg << 2);
      cprev = *(const f32x4*)(cF + (size_t)b*1024 + jj);
    }
    stage1(Win_h + ((size_t)lw << 16) + wave*16384, ldsW + wave*16384, 32);
    stage1(Win_x + (size_t)lw*20480 + wave*4096, ldsW + 65536 + wave*4096, 8);
  }
  __syncthreads();
  SCHEDB();

  u16* hB0 = hS;        u16* hB1 = hS + 65536;
  u16* cB0 = cS;        u16* cB1 = cS + 65536;

  u32 ep = 1;
  if (lw < 64) phase_incell(0, hB1, hB0, cB0);
  gsync(ep++, (lw < 64) ? Wcell + (size_t)lw*81920 : nullptr, 20480, 40, nullptr);
  int p = 1;
  #pragma unroll 1
  for (int t = 0; t < 255; ++t){
    #pragma unroll 1
    for (int i = 0; i < 4; ++i){
      u16* hIn = (p & 1) ? hB0 : hB1;  u16* cIn = (p & 1) ? cB0 : cB1;
      u16* hOut = (p & 1) ? hB1 : hB0; u16* cOut = (p & 1) ? cB1 : cB0;
      if (lw < 64)      phase_cell(i, hIn, cIn, hOut, cOut, i == 3);
      else if (i == 3)  phase_ccA(cIn);
      const u16* pf = nullptr; const u16* xs = nullptr; int cstride = 0, spw = 0;
      if (lw < 64){
        if (i < 3){ pf = Wcell + (size_t)((i+1)*64 + lw)*81920; cstride = 20480; spw = 40; }
        else      { pf = Win_h + ((size_t)lw << 16); cstride = 16384; spw = 32;
                    xs = Win_x + (size_t)lw*20480; }
      } else {
        if (i == 2){ pf = WccA + ((size_t)(lw-64) << 14); cstride = 4096; spw = 8; }
        else if (i == 3){ pf = Wout + ((size_t)(lw-64) << 16); cstride = 16384; spw = 32; }
      }
      gsync(ep++, pf, cstride, spw, xs);
      ++p;
    }
    u16* hIn = (p & 1) ? hB0 : hB1;
    u16* hOut = (p & 1) ? hB1 : hB0; u16* cOut = (p & 1) ? cB1 : cB0;
    if (lw >= 64)       phase_out(t, hIn);
    else if (t < 254)   phase_incell(t + 1, hIn, hOut, cOut);
    gsync(ep++, (lw < 64 && t < 254) ? Wcell + (size_t)lw*81920 : nullptr, 20480, 40, nullptr);
    ++p;
  }
}

// ---------------------------------------------------------------------------
// Precompute kernels
// ---------------------------------------------------------------------------

__global__ __launch_bounds__(256) void k_dense(const float* __restrict__ X, int xmode,
    const float* __restrict__ W, const float* __restrict__ bias,
    int OD, int ID, int act, int omode, float* outF, u16* outB)
{
  int o = blockIdx.x*4 + (threadIdx.x >> 6);
  if (o >= OD) return;
  int lane = threadIdx.x & 63;
  const float* wr = W + (size_t)o*ID;
  float acc = 0.f;
  if (xmode == 0){ for (int k = 0; k < ID; ++k) acc = fmaf(wr[k], X[(size_t)lane*ID + k], acc); }
  else           { for (int k = 0; k < ID; ++k) acc = fmaf(wr[k], X[(size_t)k*64 + lane], acc); }
  acc += bias[o];
  if (act) acc = acc * sigm(acc);
  if (omode == 0)      outF[(size_t)o*64 + lane] = acc;
  else if (omode == 1){
    int bt = lane >> 4, blx = lane & 15;
    outB[(size_t)bt*16384 + (size_t)(o>>5)*512 + blx*32 + ((o&31)>>3)*8 + (o&7)] = f2bf(acc);
  }
  else if (omode == 2) outF[(size_t)lane*1024 + o] = acc;
  else                 outF[(size_t)lane*81920 + 256 + o] = acc;
}

__global__ void k_zero0(float* out){ out[(size_t)blockIdx.x*81920 + threadIdx.x] = 0.f; }

// f32 -> bf16 flat convert (4 elems/thread). Grid = N/(256*4) = 4096 blocks.
__global__ void k_cvt(const float* __restrict__ src, u16* __restrict__ dst){
  int id = (blockIdx.x*256 + threadIdx.x)*4;
  f32x4 v = *(const f32x4*)(src + id);
  P4 o; o.s[0]=f2bf(v[0]); o.s[1]=f2bf(v[1]); o.s[2]=f2bf(v[2]); o.s[3]=f2bf(v[3]);
  *(u64*)(dst + id) = o.q;
}

__global__ __launch_bounds__(256) void k_tr(const float* __restrict__ in, u16* __restrict__ out, int M, int N){
  __shared__ u16 t[64][65];
  int m0 = blockIdx.x << 6, n0 = blockIdx.y << 6;
  int c = threadIdx.x & 63, rq = threadIdx.x >> 6;
  for (int rr = 0; rr < 16; ++rr){
    int r = (rq << 4) + rr;
    t[r][c] = f2bf(in[(size_t)(m0 + r)*N + n0 + c]);
  }
  __syncthreads();
  for (int rr = 0; rr < 16; ++rr){
    int r = (rq << 4) + rr;
    out[(size_t)(n0 + r)*M + m0 + c] = t[c][r];
  }
}

// Fused weight build. jt4=1 (mode 0): each block covers 64 j-rows (4 tiles
// sharing one B-fragment -> B traffic /4). jt4=0: 16 j-rows (modes 1,2).
__global__ __launch_bounds__(256) void k_fuse(const float* __restrict__ Whh,
    const u16* __restrict__ Abf, const float* __restrict__ Wih,
    const u16* __restrict__ BT, int KM, int mode, int jt4, u16* __restrict__ dst)
{
  int bx = blockIdx.x, by = blockIdx.y, bz = blockIdx.z;
  int lane = threadIdx.x & 63, wv = threadIdx.x >> 6;
  int bl = lane & 15, kg = lane >> 4;
  int jbase = (mode == 0) ? bz*1024 : ((mode == 1) ? bz*320 : 0);
  int njt = jt4 ? 4 : 1;
  int k2c = by*64 + wv*16 + bl;
  f32x4 acc0={0,0,0,0}, acc1={0,0,0,0}, acc2={0,0,0,0}, acc3={0,0,0,0};
  for (int m0 = 0; m0 < KM; m0 += 32){
    FRAG bb; bb.v = *(const bf16x8*)(BT + (size_t)k2c*KM + m0 + (kg << 3));
    #pragma unroll
    for (int jt = 0; jt < 4; ++jt){
      if (jt >= njt) break;
      int jrow = jbase + bx*(16*njt) + jt*16 + bl;
      FRAG a;
      if (Abf){
        a.v = *(const bf16x8*)(Abf + (size_t)jrow*KM + m0 + (kg << 3));
      } else {
        f32x4 wa0 = *(const f32x4*)(Whh + (size_t)jrow*KM + m0 + (kg << 3));
        f32x4 wa1 = *(const f32x4*)(Whh + (size_t)jrow*KM + m0 + (kg << 3) + 4);
        a.s[0]=f2bf(wa0[0]); a.s[1]=f2bf(wa0[1]); a.s[2]=f2bf(wa0[2]); a.s[3]=f2bf(wa0[3]);
        a.s[4]=f2bf(wa1[0]); a.s[5]=f2bf(wa1[1]); a.s[6]=f2bf(wa1[2]); a.s[7]=f2bf(wa1[3]);
      }
      if (jt == 0) acc0 = MFMA16(a.v, bb.v, acc0);
      else if (jt == 1) acc1 = MFMA16(a.v, bb.v, acc1);
      else if (jt == 2) acc2 = MFMA16(a.v, bb.v, acc2);
      else acc3 = MFMA16(a.v, bb.v, acc3);
    }
  }
  #pragma unroll
  for (int jt = 0; jt < 4; ++jt){
    if (jt >= njt) break;
    f32x4 acc = (jt == 0) ? acc0 : (jt == 1) ? acc1 : (jt == 2) ? acc2 : acc3;
    #pragma unroll
    for (int r = 0; r < 4; ++r){
      int jl = (kg << 2) + r;
      int jg = jbase + bx*(16*njt) + jt*16 + jl;
      float v = acc[r];
      if (mode < 2) v += Wih[(size_t)jg*1024 + k2c];
      int tidx = bx*njt + jt;                 // 16-row tile index
      int re = (mode == 2) ? jl : (bz*16 + jl);
      int c = k2c >> 8, kl = k2c & 255;
      size_t pos;
      if (mode == 0)      pos = (size_t)tidx*81920 + c*20480 + re*256 + (kl ^ ((re&7)<<3));
      else if (mode == 1) pos = (size_t)tidx*65536 + c*16384 + re*256 + (kl ^ ((re&7)<<3));
      else                pos = (size_t)tidx*16384 + c*4096  + re*256 + (kl ^ ((re&7)<<3));
      dst[pos] = f2bf(v);
    }
  }
}

__global__ void k_pack_winh(const float* __restrict__ src, u16* __restrict__ dst){
  int id = blockIdx.x*256 + threadIdx.x;
  int j = id >> 10, k = id & 1023;
  int g = j >> 10, jj = j & 1023;
  int w = jj >> 4, r = (g << 4) + (jj & 15);
  int c = k >> 8, kl = k & 255;
  dst[(size_t)w*65536 + c*16384 + r*256 + (kl ^ ((r&7)<<3))] = f2bf(src[id]);
}

__global__ void k_pack_winx(const float* __restrict__ src, u16* __restrict__ dst){
  int j = blockIdx.x, k = threadIdx.x;
  int g = j >> 10, jj = j & 1023;
  int w = jj >> 4, r = (g << 4) + (jj & 15);
  float v = src[(size_t)j*320 + k];
  size_t pos;
  if (k < 256) pos = (size_t)w*20480 + r*256 + (k ^ ((r&7)<<3));
  else         pos = (size_t)w*20480 + 16384 + r*64 + ((k - 256) ^ ((r&7)<<3));
  dst[pos] = f2bf(v);
}

__global__ void k_pack_ca(const float* __restrict__ src, u16* __restrict__ dst){
  int id = blockIdx.x*256 + threadIdx.x;
  int jj = id >> 10, k = id & 1023;
  int w = jj >> 4, r = 64 + (jj & 15);
  int c = k >> 8, kl = k & 255;
  dst[(size_t)w*81920 + c*20480 + r*256 + (kl ^ ((r&7)<<3))] = f2bf(src[id]);
}

__global__ __launch_bounds__(256) void k_bias(const float* __restrict__ A, const float* __restrict__ x,
    const float* __restrict__ a1, const float* __restrict__ a2, float* __restrict__ o, int NJ, int K)
{
  int j = blockIdx.x*4 + (threadIdx.x >> 6);
  if (j >= NJ) return;
  int lane = threadIdx.x & 63;
  float acc = 0.f;
  if (A) for (int k = lane; k < K; k += 64) acc += A[(size_t)j*K + k]*x[k];
  for (int off = 32; off; off >>= 1) acc += __shfl_down(acc, off);
  if (lane == 0) o[j] = acc + (a1 ? a1[j] : 0.f) + (a2 ? a2[j] : 0.f);
}

// ---------------------------------------------------------------------------
extern "C" void kernel_launch(void* const* d_in, const int* in_sizes, int n_in,
                              void* d_out, int out_size, void* d_ws, size_t ws_size,
                              hipStream_t stream)
{
  (void)in_sizes; (void)n_in; (void)out_size;
  const float* z      = (const float*)d_in[0];
  const float* m_true = (const float*)d_in[1];
  const float* eh_W1=(const float*)d_in[2],  *eh_b1=(const float*)d_in[3];
  const float* eh_W2=(const float*)d_in[4],  *eh_b2=(const float*)d_in[5];
  const float* eh_W3=(const float*)d_in[6],  *eh_b3=(const float*)d_in[7];
  const float* ec_W1=(const float*)d_in[8],  *ec_b1=(const float*)d_in[9];
  const float* ec_W2=(const float*)d_in[10], *ec_b2=(const float*)d_in[11];
  const float* ec_W3=(const float*)d_in[12], *ec_b3=(const float*)d_in[13];
  const float* ex_W1=(const float*)d_in[14], *ex_b1=(const float*)d_in[15];
  const float* ex_W2=(const float*)d_in[16], *ex_b2=(const float*)d_in[17];
  const float* ex_W3=(const float*)d_in[18], *ex_b3=(const float*)d_in[19];
  const float* in_Wih=(const float*)d_in[20], *in_Whh=(const float*)d_in[21];
  const float* in_bih=(const float*)d_in[22], *in_bhh=(const float*)d_in[23];
  const float* r_Wih=(const float*)d_in[24],  *r_Whh=(const float*)d_in[25];
  const float* r_bih=(const float*)d_in[26],  *r_bhh=(const float*)d_in[27];
  const float* hA_W=(const float*)d_in[28],   *hA_b=(const float*)d_in[29];
  const float* cA_W=(const float*)d_in[30],   *cA_b=(const float*)d_in[31];
  const float* lastH_W=(const float*)d_in[32], *lastH_b=(const float*)d_in[33];
  const float* lastC_W=(const float*)d_in[34], *lastC_b=(const float*)d_in[35];
  const float* out_Wih=(const float*)d_in[36], *out_Whh=(const float*)d_in[37];
  const float* out_bih=(const float*)d_in[38], *out_bhh=(const float*)d_in[39];
  float* out = (float*)d_out;

  char* wsb = (char*)d_ws;
  size_t off = 0;
  auto alloc = [&](size_t bytes)->char*{
    char* p = wsb + off; off = (off + bytes + 255) & ~(size_t)255; return p;
  };
  u32* bar    = (u32*)alloc(256*32*4);
  u16* hS     = (u16*)alloc(2*64*1024*2);
  u16* cS     = (u16*)alloc(2*64*1024*2);
  float* cF   = (float*)alloc(64*1024*4);
  float* b_in = (float*)alloc(4096*4);
  float* b_cell=(float*)alloc(4*4096*4);
  float* b_out= (float*)alloc(1280*4);
  float* b_cc = (float*)alloc(320*4);
  float* t1   = (float*)alloc(1024*64*4);
  float* t2   = (float*)alloc(1024*64*4);
  u16* Tbuf   = (u16*)alloc((size_t)1024*1024*2);
  u16* Wbf    = (u16*)alloc((size_t)4096*1024*2);
  u16* Win_h  = (u16*)alloc((size_t)64*65536*2);
  u16* Win_x  = (u16*)alloc((size_t)64*20480*2);
  u16* Wcell  = (u16*)alloc((size_t)4*64*81920*2);
  u16* Wout   = (u16*)alloc((size_t)20*65536*2);
  u16* WccA   = (u16*)alloc((size_t)20*16384*2);
  if (off > ws_size) return;

  hipMemsetAsync(bar, 0, 256*32*4, stream);

  k_dense<<<256,256,0,stream>>>(z, 0, eh_W1, eh_b1, 1024, 256, 1, 0, t1, nullptr);
  k_dense<<<256,256,0,stream>>>(t1,1, eh_W2, eh_b2, 1024,1024, 1, 0, t2, nullptr);
  k_dense<<<256,256,0,stream>>>(t2,1, eh_W3, eh_b3, 1024,1024, 0, 1, nullptr, hS + 65536);
  k_dense<<<256,256,0,stream>>>(z, 0, ec_W1, ec_b1, 1024, 256, 1, 0, t1, nullptr);
  k_dense<<<256,256,0,stream>>>(t1,1, ec_W2, ec_b2, 1024,1024, 1, 0, t2, nullptr);
  k_dense<<<256,256,0,stream>>>(t2,1, ec_W3, ec_b3, 1024,1024, 0, 2, cF, nullptr);
  k_dense<<<256,256,0,stream>>>(z, 0, ex_W1, ex_b1, 1024, 256, 1, 0, t1, nullptr);
  k_dense<<<256,256,0,stream>>>(t1,1, ex_W2, ex_b2, 1024,1024, 1, 0, t2, nullptr);
  k_dense<<<16 ,256,0,stream>>>(t2,1, ex_W3, ex_b3,   64,1024, 0, 3, out, nullptr);
  k_zero0<<<64,256,0,stream>>>(out);

  k_pack_winh<<<16384,256,0,stream>>>(in_Whh, Win_h);
  k_pack_winx<<<4096,320,0,stream>>>(in_Wih, Win_x);
  for (int i = 0; i < 4; ++i)
    k_pack_ca<<<4096,256,0,stream>>>(cA_W + (size_t)i*1024*1024, Wcell + (size_t)i*64*81920);

  for (int i = 0; i < 4; ++i){
    k_cvt<<<4096,256,0,stream>>>(r_Whh + (size_t)i*4096*1024, Wbf);
    k_tr<<<dim3(16,16),256,0,stream>>>(hA_W + (size_t)i*1024*1024, Tbuf, 1024, 1024);
    k_fuse<<<dim3(16,16,4),256,0,stream>>>(nullptr, Wbf,
                                           r_Wih + (size_t)i*4096*1024,
                                           Tbuf, 1024, 0, 1, Wcell + (size_t)i*64*81920);
  }
  k_tr<<<dim3(5,16),256,0,stream>>>(lastH_W, Tbuf, 320, 1024);
  k_fuse<<<dim3(20,16,4),256,0,stream>>>(out_Whh, nullptr, out_Wih, Tbuf, 320, 1, 0, Wout);
  k_tr<<<dim3(16,16),256,0,stream>>>(cA_W + (size_t)3*1024*1024, Tbuf, 1024, 1024);
  k_fuse<<<dim3(20,16,1),256,0,stream>>>(lastC_W, nullptr, nullptr, Tbuf, 1024, 2, 0, WccA);

  k_bias<<<1024,256,0,stream>>>(nullptr, nullptr, in_bih, in_bhh, b_in, 4096, 0);
  for (int i = 0; i < 4; ++i)
    k_bias<<<1024,256,0,stream>>>(r_Whh + (size_t)i*4096*1024, hA_b + i*1024,
                                  r_bih + i*4096, r_bhh + i*4096, b_cell + i*4096, 4096, 1024);
  k_bias<<<320,256,0,stream>>>(out_Whh, lastH_b, out_bih, out_bhh, b_out, 1280, 320);
  k_bias<<<80 ,256,0,stream>>>(lastC_W, cA_b + 3*1024, lastC_b, nullptr, b_cc, 320, 1024);

  k_scan<<<NWG,256,0,stream>>>(m_true, Wcell, Win_h, Win_x, Wout, WccA,
                               b_in, b_cell, cA_b, b_out, b_cc,
                               hS, cS, cF, out, bar);
}

// Round 14
// 11471.933 us; speedup vs baseline: 1.3346x; 1.0097x over previous
//
#include <hip/hip_runtime.h>

// BigARDecoder: persistent-kernel LSTM scan on MI355X.
// B=64, T=256, IN=256, H=1024, G=256, O=64, D=4, GO=320.
//
// R14 = R12 verbatim (best passing: 11.58ms total, k_scan 9.65ms).
// R13's packed-flag experiment REVERTED: sharing flag cache lines between
// producer stores and the consumer poll raced (absmax 0.084, nondet).
// Flags stay on exclusive 128B lines. Scan = R8 structure: masterless
// padded-flag barrier, sc0/sc1 counted state loads, register carries,
// 4-wave K-split, whole-phase weight staging inside the barrier window.
// Precompute: bf16 A-operand (k_cvt) + 4x j-tiled k_fuse.

typedef unsigned int u32;
typedef unsigned long long u64;
typedef unsigned short u16;
typedef __attribute__((ext_vector_type(8))) __bf16 bf16x8;
typedef __attribute__((ext_vector_type(4))) float f32x4;

#define DEVI __device__ __forceinline__

union FRAG { bf16x8 v; u16 s[8]; u64 q[2]; };
union P4 { u64 q; u16 s[4]; };
union F4 { u64 q[2]; float f[4]; };

DEVI u16 f2bf(float x){ u32 u = __float_as_uint(x); return (u16)((u + 0x7fffu + ((u>>16)&1u)) >> 16); }
DEVI float sigm(float x){ return 1.0f/(1.0f + __expf(-x)); }
DEVI float tanh_(float x){ return 2.0f/(1.0f + __expf(-2.0f*x)) - 1.0f; }
DEVI void ast(void* p, u64 v){ __hip_atomic_store((u64*)p, v, __ATOMIC_RELAXED, __HIP_MEMORY_SCOPE_AGENT); }

// counted asm loads (issue order == program order of volatiles == vmcnt FIFO)
DEVI void ld16sc(FRAG& d, const void* p){
  asm volatile("global_load_dwordx4 %0, %1, off sc0 sc1" : "=v"(d.v) : "v"(p));
}
DEVI void ld16(FRAG& d, const void* p){
  asm volatile("global_load_dwordx4 %0, %1, off" : "=v"(d.v) : "v"(p));
}
DEVI void ldf4(f32x4& d, const void* p){
  asm volatile("global_load_dwordx4 %0, %1, off" : "=v"(d) : "v"(p));
}

#define MFMA16(a,b,c) __builtin_amdgcn_mfma_f32_16x16x32_bf16(a, b, c, 0, 0, 0)

#define NWG 168

#define SCHEDB() __builtin_amdgcn_sched_barrier(0)
#define WAITV(n) do{ SCHEDB(); \
  asm volatile("s_waitcnt vmcnt(" #n ")" ::: "memory"); \
  SCHEDB(); }while(0)

// ---------------------------------------------------------------------------
// Persistent scan kernel. 168 WGs x 256 threads (no master).
// wg -> (pipe, lw): twins 8 apart (same XCD). lw 0..63: hidden tiles;
// lw 64..83: out-cell / ccA tiles. Wave w = (pair=w>>1 K-half, bt=(pipe<<1)+(w&1)).
// State frag layout (per buffer, 128KB): [btile(4)][ks(32)][bl(16)][kg(4)][8 bf16]
// LDS: 160KB weight chunks. Flags: bar + (pipe*128 + lw)*32 (128B lines).
// ---------------------------------------------------------------------------
__global__ __launch_bounds__(256, 1) void k_scan(
    const float* __restrict__ m_true,
    const u16* __restrict__ Wcell, const u16* __restrict__ Win_h,
    const u16* __restrict__ Win_x, const u16* __restrict__ Wout,
    const u16* __restrict__ WccA,
    const float* __restrict__ b_in, const float* __restrict__ b_cell,
    const float* __restrict__ cAb, const float* __restrict__ b_out,
    const float* __restrict__ b_cc,
    u16* hS, u16* cS, float* cF, float* outp, u32* bar)
{
  const int wg = blockIdx.x;
  const int tid = threadIdx.x;
  const int wave = tid >> 6, lane = tid & 63;

  int pipe, lw;
  if (wg < 160){ pipe = (wg >> 3) & 1; lw = ((wg >> 4) << 3) | (wg & 7); }
  else         { pipe = (wg - 160) >> 2; lw = 80 + ((wg - 160) & 3); }

  const int bl = lane & 15, kg = lane >> 4;
  const int pair = wave >> 1;               // K-half this wave owns
  const int bt = (pipe << 1) + (wave & 1);  // btile this wave owns
  const int b  = (bt << 4) + bl;
  const int swz = (bl & 7) << 4;
  const int foff = ((bl << 2) + kg) << 4;
  const int woff = (bt << 15) + ((lw >> 1) << 10) + (bl << 6) + ((lw & 1) << 5) + (kg << 3);
  u32* flagp = bar + (pipe*128 + lw)*32;
  const u32* fbase = bar + pipe*128*32;
  const int i2 = (lane < 20) ? 64 + lane : lane;   // poll coverage 0..83
  __shared__ __align__(16) u16 ldsW[81920];   // 160KB weight chunks

  f32x4 cprev = {0,0,0,0};   // cell WGs (wave<2): c carry cell3 -> in-cell
  f32x4 ccreg = {0,0,0,0};   // out  WGs (wave<2): cc carry ccA -> out

  auto stage1 = [&](const u16* src, u16* lb, int segs){
    const u16* g = src + (lane << 3);
    u16* l = lb;
    for (int s = 0; s < segs; ++s){
      __builtin_amdgcn_global_load_lds(
          (const __attribute__((address_space(1))) void*)g,
          (__attribute__((address_space(3))) void*)l, 16, 0, 0);
      g += 512; l += 512;
    }
    SCHEDB();
  };
  auto afL = [&](const u16* lb, int row, int kb) -> bf16x8 {
    return *(const bf16x8*)((const char*)lb + row*512 + (kb ^ swz));
  };

  // masterless barrier: flag bump; each wave stages its own next-phase chunk;
  // wave 0 polls all 84 flags of this pipeline directly.
  auto gsync = [&](u32 ep, const u16* pfsrc, int cstride, int spw, const u16* xsrc){
    SCHEDB();
    __syncthreads();                  // per-wave vmcnt(0): state stores acked
    if (tid == 0)
      __hip_atomic_store(flagp, ep, __ATOMIC_RELAXED, __HIP_MEMORY_SCOPE_AGENT);
    SCHEDB();
    if (pfsrc) stage1(pfsrc + (size_t)wave*cstride, ldsW + wave*cstride, spw);
    if (xsrc)  stage1(xsrc + wave*4096, ldsW + 65536 + wave*4096, 8);
    SCHEDB();
    if (wave == 0){
      for(;;){
        u32 a = __hip_atomic_load(fbase + lane*32, __ATOMIC_RELAXED, __HIP_MEMORY_SCOPE_AGENT);
        u32 c2 = __hip_atomic_load(fbase + i2*32, __ATOMIC_RELAXED, __HIP_MEMORY_SCOPE_AGENT);
        if (__all(a >= ep && c2 >= ep)) break;
        __builtin_amdgcn_s_sleep(1);
      }
    }
    __syncthreads();                  // broadcast + drain weight stage
    SCHEDB();
  };

  // ---- in-cell phase (lw<64). entry: ch0..3 = Win_h, ch4 = Win_x part1 ----
  auto phase_incell = [&](int t, const u16* hIn, u16* hOut, u16* cOut){
    f32x4 A0={0,0,0,0}, A1={0,0,0,0}, A2={0,0,0,0}, A3={0,0,0,0};
    const char* hf = (const char*)hIn + (bt << 15) + foff;
    const int ksb = pair << 4;
    int jl = (kg << 2), jj = (lw << 4) + jl;
    FRAG sh[2][8], pa[8];
    f32x4 bg0, bg1, bg2, bg3;
    // counted issue: hL1(8) hL2(8) pa(8) bias(4) = 28
    #pragma unroll
    for (int ks = 0; ks < 8; ++ks) ld16sc(sh[0][ks], hf + (ksb + ks)*1024);
    #pragma unroll
    for (int ks = 0; ks < 8; ++ks) ld16sc(sh[1][ks], hf + (ksb + 8 + ks)*1024);
    {
      const char* p2 = (const char*)(Win_x + (size_t)lw*20480 + 16384);
      #pragma unroll
      for (int k2 = 0; k2 < 2; ++k2)
        #pragma unroll
        for (int rb = 0; rb < 4; ++rb)
          ld16(pa[k2*4+rb], p2 + (rb*16 + bl)*128 + (((k2<<6)+(kg<<4)) ^ swz));
    }
    ldf4(bg0, b_in +        jj);
    ldf4(bg1, b_in + 1024 + jj);
    ldf4(bg2, b_in + 2048 + jj);
    ldf4(bg3, b_in + 3072 + jj);
    WAITV(20);
    const u16* lbA = ldsW + (pair*2)*16384;
    #pragma unroll
    for (int ks = 0; ks < 8; ++ks){
      int kb = (ks << 6) + (kg << 4);
      FRAG a;
      a.v = afL(lbA, bl, kb);      A0 = MFMA16(a.v, sh[0][ks].v, A0);
      a.v = afL(lbA, 16 + bl, kb); A1 = MFMA16(a.v, sh[0][ks].v, A1);
      a.v = afL(lbA, 32 + bl, kb); A2 = MFMA16(a.v, sh[0][ks].v, A2);
      a.v = afL(lbA, 48 + bl, kb); A3 = MFMA16(a.v, sh[0][ks].v, A3);
    }
    WAITV(12);
    const u16* lbB = ldsW + (pair*2+1)*16384;
    #pragma unroll
    for (int ks = 0; ks < 8; ++ks){
      int kb = (ks << 6) + (kg << 4);
      FRAG a;
      a.v = afL(lbB, bl, kb);      A0 = MFMA16(a.v, sh[1][ks].v, A0);
      a.v = afL(lbB, 16 + bl, kb); A1 = MFMA16(a.v, sh[1][ks].v, A1);
      a.v = afL(lbB, 32 + bl, kb); A2 = MFMA16(a.v, sh[1][ks].v, A2);
      a.v = afL(lbB, 48 + bl, kb); A3 = MFMA16(a.v, sh[1][ks].v, A3);
    }
    WAITV(4);                               // pa landed (bias outstanding)
    if (wave >= 2){                         // x contribution (pair B only)
      FRAG xf[10];
      const float* xr = m_true + (size_t)b*81920 + (size_t)(255 - t)*320;
      #pragma unroll
      for (int ks = 0; ks < 10; ++ks){
        int k = (ks << 5) + (kg << 3);
        f32x4 x0 = *(const f32x4*)(xr + k);
        f32x4 x1 = *(const f32x4*)(xr + k + 4);
        xf[ks].s[0]=f2bf(x0[0]); xf[ks].s[1]=f2bf(x0[1]); xf[ks].s[2]=f2bf(x0[2]); xf[ks].s[3]=f2bf(x0[3]);
        xf[ks].s[4]=f2bf(x1[0]); xf[ks].s[5]=f2bf(x1[1]); xf[ks].s[6]=f2bf(x1[2]); xf[ks].s[7]=f2bf(x1[3]);
      }
      const u16* lb4 = ldsW + 65536;
      #pragma unroll
      for (int ks = 0; ks < 8; ++ks){
        int kb = (ks << 6) + (kg << 4);
        FRAG a;
        a.v = afL(lb4, bl, kb);      A0 = MFMA16(a.v, xf[ks].v, A0);
        a.v = afL(lb4, 16 + bl, kb); A1 = MFMA16(a.v, xf[ks].v, A1);
        a.v = afL(lb4, 32 + bl, kb); A2 = MFMA16(a.v, xf[ks].v, A2);
        a.v = afL(lb4, 48 + bl, kb); A3 = MFMA16(a.v, xf[ks].v, A3);
      }
      #pragma unroll
      for (int k2 = 0; k2 < 2; ++k2){
        A0 = MFMA16(pa[k2*4+0].v, xf[8+k2].v, A0);
        A1 = MFMA16(pa[k2*4+1].v, xf[8+k2].v, A1);
        A2 = MFMA16(pa[k2*4+2].v, xf[8+k2].v, A2);
        A3 = MFMA16(pa[k2*4+3].v, xf[8+k2].v, A3);
      }
    }
    __syncthreads();                        // also drains bias/xf
    float* red = (float*)ldsW;
    if (wave >= 2){
      float* r = red + ((wave&1)*64 + lane)*20;
      *(f32x4*)(r+0) = A0; *(f32x4*)(r+4) = A1;
      *(f32x4*)(r+8) = A2; *(f32x4*)(r+12) = A3;
    }
    __syncthreads();
    if (wave < 2){
      const float* r = red + ((wave&1)*64 + lane)*20;
      A0 += *(const f32x4*)(r+0); A1 += *(const f32x4*)(r+4);
      A2 += *(const f32x4*)(r+8); A3 += *(const f32x4*)(r+12);
      P4 hw, cw;
      #pragma unroll
      for (int rr = 0; rr < 4; ++rr){
        float gi = A0[rr] + bg0[rr];
        float gf = A1[rr] + bg1[rr];
        float gg = A2[rr] + bg2[rr];
        float go = A3[rr] + bg3[rr];
        float cn = sigm(gf)*cprev[rr] + sigm(gi)*tanh_(gg);
        hw.s[rr] = f2bf(sigm(go)*tanh_(cn));
        cw.s[rr] = f2bf(cn);
      }
      ast((char*)hOut + woff, hw.q);
      ast((char*)cOut + woff, cw.q);
    }
  };

  // ---- inner cell phase i (lw<64). entry: ch0..3 = Wcell_i ----
  auto phase_cell = [&](int i, const u16* hIn, const u16* cIn, u16* hOut, u16* cOut, bool last){
    f32x4 A0={0,0,0,0}, A1={0,0,0,0}, A2={0,0,0,0}, A3={0,0,0,0}, A4={0,0,0,0};
    const char* hf  = (const char*)hIn + (bt << 15) + foff;
    const char* cfr = (const char*)cIn + (bt << 15) + foff;
    const int ksb = pair << 4;
    int jl = (kg << 2), jj = (lw << 4) + jl;
    FRAG sh[2][8], sc[2][8];
    f32x4 bg0, bg1, bg2, bg3, bca;
    // counted issue: hL1(8) cL1(8) hL2(8) cL2(8) bias(5) = 37
    #pragma unroll
    for (int ks = 0; ks < 8; ++ks) ld16sc(sh[0][ks], hf  + (ksb + ks)*1024);
    #pragma unroll
    for (int ks = 0; ks < 8; ++ks) ld16sc(sc[0][ks], cfr + (ksb + ks)*1024);
    #pragma unroll
    for (int ks = 0; ks < 8; ++ks) ld16sc(sh[1][ks], hf  + (ksb + 8 + ks)*1024);
    #pragma unroll
    for (int ks = 0; ks < 8; ++ks) ld16sc(sc[1][ks], cfr + (ksb + 8 + ks)*1024);
    ldf4(bg0, b_cell + i*4096 +        jj);
    ldf4(bg1, b_cell + i*4096 + 1024 + jj);
    ldf4(bg2, b_cell + i*4096 + 2048 + jj);
    ldf4(bg3, b_cell + i*4096 + 3072 + jj);
    ldf4(bca, cAb + i*1024 + jj);
    WAITV(21);
    const u16* lbA = ldsW + (pair*2)*20480;
    #pragma unroll
    for (int ks = 0; ks < 8; ++ks){
      int kb = (ks << 6) + (kg << 4);
      FRAG a;
      a.v = afL(lbA, bl, kb);      A0 = MFMA16(a.v, sh[0][ks].v, A0);
      a.v = afL(lbA, 16 + bl, kb); A1 = MFMA16(a.v, sh[0][ks].v, A1);
      a.v = afL(lbA, 32 + bl, kb); A2 = MFMA16(a.v, sh[0][ks].v, A2);
      a.v = afL(lbA, 48 + bl, kb); A3 = MFMA16(a.v, sh[0][ks].v, A3);
      a.v = afL(lbA, 64 + bl, kb); A4 = MFMA16(a.v, sc[0][ks].v, A4);
    }
    WAITV(5);
    const u16* lbB = ldsW + (pair*2+1)*20480;
    #pragma unroll
    for (int ks = 0; ks < 8; ++ks){
      int kb = (ks << 6) + (kg << 4);
      FRAG a;
      a.v = afL(lbB, bl, kb);      A0 = MFMA16(a.v, sh[1][ks].v, A0);
      a.v = afL(lbB, 16 + bl, kb); A1 = MFMA16(a.v, sh[1][ks].v, A1);
      a.v = afL(lbB, 32 + bl, kb); A2 = MFMA16(a.v, sh[1][ks].v, A2);
      a.v = afL(lbB, 48 + bl, kb); A3 = MFMA16(a.v, sh[1][ks].v, A3);
      a.v = afL(lbB, 64 + bl, kb); A4 = MFMA16(a.v, sc[1][ks].v, A4);
    }
    __syncthreads();
    float* red = (float*)ldsW;
    if (wave >= 2){
      float* r = red + ((wave&1)*64 + lane)*20;
      *(f32x4*)(r+0) = A0; *(f32x4*)(r+4) = A1;
      *(f32x4*)(r+8) = A2; *(f32x4*)(r+12) = A3; *(f32x4*)(r+16) = A4;
    }
    __syncthreads();
    if (wave < 2){
      const float* r = red + ((wave&1)*64 + lane)*20;
      A0 += *(const f32x4*)(r+0); A1 += *(const f32x4*)(r+4);
      A2 += *(const f32x4*)(r+8); A3 += *(const f32x4*)(r+12);
      A4 += *(const f32x4*)(r+16);
      P4 hw, cw; F4 cf4;
      #pragma unroll
      for (int rr = 0; rr < 4; ++rr){
        float gi = A0[rr] + bg0[rr];
        float gf = A1[rr] + bg1[rr];
        float gg = A2[rr] + bg2[rr];
        float go = A3[rr] + bg3[rr];
        float c1 = A4[rr] + bca[rr];
        float cn = sigm(gf)*c1 + sigm(gi)*tanh_(gg);
        hw.s[rr] = f2bf(sigm(go)*tanh_(cn));
        cw.s[rr] = f2bf(cn);
        cf4.f[rr] = cn;
      }
      ast((char*)hOut + woff, hw.q);
      ast((char*)cOut + woff, cw.q);
      if (last){ cprev[0]=cf4.f[0]; cprev[1]=cf4.f[1]; cprev[2]=cf4.f[2]; cprev[3]=cf4.f[3]; }
    }
  };

  // ---- ccA phase (lw 64..83, with cell i==3). entry: ch0..3 = WccA ----
  auto phase_ccA = [&](const u16* cIn){
    f32x4 A = {0,0,0,0};
    const char* cfr = (const char*)cIn + (bt << 15) + foff;
    const int ksb = pair << 4;
    int jl = (kg << 2), jjo = ((lw - 64) << 4) + jl;
    FRAG sc[2][8];
    f32x4 bcc;
    // counted issue: cL1(8) cL2(8) bcc(1) = 17
    #pragma unroll
    for (int ks = 0; ks < 8; ++ks) ld16sc(sc[0][ks], cfr + (ksb + ks)*1024);
    #pragma unroll
    for (int ks = 0; ks < 8; ++ks) ld16sc(sc[1][ks], cfr + (ksb + 8 + ks)*1024);
    ldf4(bcc, b_cc + jjo);
    WAITV(9);
    const u16* lbA = ldsW + (pair*2)*4096;
    #pragma unroll
    for (int ks = 0; ks < 8; ++ks){
      int kb = (ks << 6) + (kg << 4);
      FRAG a; a.v = afL(lbA, bl, kb);
      A = MFMA16(a.v, sc[0][ks].v, A);
    }
    WAITV(1);
    const u16* lbB = ldsW + (pair*2+1)*4096;
    #pragma unroll
    for (int ks = 0; ks < 8; ++ks){
      int kb = (ks << 6) + (kg << 4);
      FRAG a; a.v = afL(lbB, bl, kb);
      A = MFMA16(a.v, sc[1][ks].v, A);
    }
    __syncthreads();
    float* red = (float*)ldsW;
    if (wave >= 2) *(f32x4*)(red + ((wave&1)*64 + lane)*20) = A;
    __syncthreads();
    if (wave < 2){
      A += *(const f32x4*)(red + ((wave&1)*64 + lane)*20);
      #pragma unroll
      for (int rr = 0; rr < 4; ++rr) ccreg[rr] = A[rr] + bcc[rr];
    }
  };

  // ---- out-cell phase (lw 64..83). entry: ch0..3 = Wout ----
  auto phase_out = [&](int t, const u16* hIn){
    f32x4 A0={0,0,0,0}, A1={0,0,0,0}, A2={0,0,0,0}, A3={0,0,0,0};
    const char* hf = (const char*)hIn + (bt << 15) + foff;
    const int ksb = pair << 4;
    int jl = (kg << 2), jjo = ((lw - 64) << 4) + jl;
    FRAG sh[2][8];
    f32x4 bg0, bg1, bg2, bg3;
    // counted issue: hL1(8) hL2(8) bias(4) = 20
    #pragma unroll
    for (int ks = 0; ks < 8; ++ks) ld16sc(sh[0][ks], hf + (ksb + ks)*1024);
    #pragma unroll
    for (int ks = 0; ks < 8; ++ks) ld16sc(sh[1][ks], hf + (ksb + 8 + ks)*1024);
    ldf4(bg0, b_out +       jjo);
    ldf4(bg1, b_out + 320 + jjo);
    ldf4(bg2, b_out + 640 + jjo);
    ldf4(bg3, b_out + 960 + jjo);
    WAITV(12);
    const u16* lbA = ldsW + (pair*2)*16384;
    #pragma unroll
    for (int ks = 0; ks < 8; ++ks){
      int kb = (ks << 6) + (kg << 4);
      FRAG a;
      a.v = afL(lbA, bl, kb);      A0 = MFMA16(a.v, sh[0][ks].v, A0);
      a.v = afL(lbA, 16 + bl, kb); A1 = MFMA16(a.v, sh[0][ks].v, A1);
      a.v = afL(lbA, 32 + bl, kb); A2 = MFMA16(a.v, sh[0][ks].v, A2);
      a.v = afL(lbA, 48 + bl, kb); A3 = MFMA16(a.v, sh[0][ks].v, A3);
    }
    WAITV(4);
    const u16* lbB = ldsW + (pair*2+1)*16384;
    #pragma unroll
    for (int ks = 0; ks < 8; ++ks){
      int kb = (ks << 6) + (kg << 4);
      FRAG a;
      a.v = afL(lbB, bl, kb);      A0 = MFMA16(a.v, sh[1][ks].v, A0);
      a.v = afL(lbB, 16 + bl, kb); A1 = MFMA16(a.v, sh[1][ks].v, A1);
      a.v = afL(lbB, 32 + bl, kb); A2 = MFMA16(a.v, sh[1][ks].v, A2);
      a.v = afL(lbB, 48 + bl, kb); A3 = MFMA16(a.v, sh[1][ks].v, A3);
    }
    __syncthreads();
    float* red = (float*)ldsW;
    if (wave >= 2){
      float* r = red + ((wave&1)*64 + lane)*20;
      *(f32x4*)(r+0) = A0; *(f32x4*)(r+4) = A1;
      *(f32x4*)(r+8) = A2; *(f32x4*)(r+12) = A3;
    }
    __syncthreads();
    if (wave < 2){
      const float* r = red + ((wave&1)*64 + lane)*20;
      A0 += *(const f32x4*)(r+0); A1 += *(const f32x4*)(r+4);
      A2 += *(const f32x4*)(r+8); A3 += *(const f32x4*)(r+12);
      f32x4 ho;
      #pragma unroll
      for (int rr = 0; rr < 4; ++rr){
        float gi = A0[rr] + bg0[rr];
        float gf = A1[rr] + bg1[rr];
        float gg = A2[rr] + bg2[rr];
        float go = A3[rr] + bg3[rr];
        float cn = sigm(gf)*ccreg[rr] + sigm(gi)*tanh_(gg);
        ho[rr] = sigm(go)*tanh_(cn);
      }
      *(f32x4*)(outp + (size_t)b*81920 + (size_t)(t+1)*320 + jjo) = ho;
    }
  };

  // ---- init: cprev from cF (written by k_dense), first incell weights ----
  if (lw < 64){
    if (wave < 2){
      int jj = (lw << 4) + (kg << 2);
      cprev = *(const f32x4*)(cF + (size_t)b*1024 + jj);
    }
    stage1(Win_h + ((size_t)lw << 16) + wave*16384, ldsW + wave*16384, 32);
    stage1(Win_x + (size_t)lw*20480 + wave*4096, ldsW + 65536 + wave*4096, 8);
  }
  __syncthreads();
  SCHEDB();

  u16* hB0 = hS;        u16* hB1 = hS + 65536;
  u16* cB0 = cS;        u16* cB1 = cS + 65536;

  u32 ep = 1;
  if (lw < 64) phase_incell(0, hB1, hB0, cB0);
  gsync(ep++, (lw < 64) ? Wcell + (size_t)lw*81920 : nullptr, 20480, 40, nullptr);
  int p = 1;
  #pragma unroll 1
  for (int t = 0; t < 255; ++t){
    #pragma unroll 1
    for (int i = 0; i < 4; ++i){
      u16* hIn = (p & 1) ? hB0 : hB1;  u16* cIn = (p & 1) ? cB0 : cB1;
      u16* hOut = (p & 1) ? hB1 : hB0; u16* cOut = (p & 1) ? cB1 : cB0;
      if (lw < 64)      phase_cell(i, hIn, cIn, hOut, cOut, i == 3);
      else if (i == 3)  phase_ccA(cIn);
      const u16* pf = nullptr; const u16* xs = nullptr; int cstride = 0, spw = 0;
      if (lw < 64){
        if (i < 3){ pf = Wcell + (size_t)((i+1)*64 + lw)*81920; cstride = 20480; spw = 40; }
        else      { pf = Win_h + ((size_t)lw << 16); cstride = 16384; spw = 32;
                    xs = Win_x + (size_t)lw*20480; }
      } else {
        if (i == 2){ pf = WccA + ((size_t)(lw-64) << 14); cstride = 4096; spw = 8; }
        else if (i == 3){ pf = Wout + ((size_t)(lw-64) << 16); cstride = 16384; spw = 32; }
      }
      gsync(ep++, pf, cstride, spw, xs);
      ++p;
    }
    u16* hIn = (p & 1) ? hB0 : hB1;
    u16* hOut = (p & 1) ? hB1 : hB0; u16* cOut = (p & 1) ? cB1 : cB0;
    if (lw >= 64)       phase_out(t, hIn);
    else if (t < 254)   phase_incell(t + 1, hIn, hOut, cOut);
    gsync(ep++, (lw < 64 && t < 254) ? Wcell + (size_t)lw*81920 : nullptr, 20480, 40, nullptr);
    ++p;
  }
}

// ---------------------------------------------------------------------------
// Precompute kernels
// ---------------------------------------------------------------------------

__global__ __launch_bounds__(256) void k_dense(const float* __restrict__ X, int xmode,
    const float* __restrict__ W, const float* __restrict__ bias,
    int OD, int ID, int act, int omode, float* outF, u16* outB)
{
  int o = blockIdx.x*4 + (threadIdx.x >> 6);
  if (o >= OD) return;
  int lane = threadIdx.x & 63;
  const float* wr = W + (size_t)o*ID;
  float acc = 0.f;
  if (xmode == 0){ for (int k = 0; k < ID; ++k) acc = fmaf(wr[k], X[(size_t)lane*ID + k], acc); }
  else           { for (int k = 0; k < ID; ++k) acc = fmaf(wr[k], X[(size_t)k*64 + lane], acc); }
  acc += bias[o];
  if (act) acc = acc * sigm(acc);
  if (omode == 0)      outF[(size_t)o*64 + lane] = acc;
  else if (omode == 1){
    int bt = lane >> 4, blx = lane & 15;
    outB[(size_t)bt*16384 + (size_t)(o>>5)*512 + blx*32 + ((o&31)>>3)*8 + (o&7)] = f2bf(acc);
  }
  else if (omode == 2) outF[(size_t)lane*1024 + o] = acc;
  else                 outF[(size_t)lane*81920 + 256 + o] = acc;
}

__global__ void k_zero0(float* out){ out[(size_t)blockIdx.x*81920 + threadIdx.x] = 0.f; }

// f32 -> bf16 flat convert (4 elems/thread). Grid = N/(256*4) = 4096 blocks.
__global__ void k_cvt(const float* __restrict__ src, u16* __restrict__ dst){
  int id = (blockIdx.x*256 + threadIdx.x)*4;
  f32x4 v = *(const f32x4*)(src + id);
  P4 o; o.s[0]=f2bf(v[0]); o.s[1]=f2bf(v[1]); o.s[2]=f2bf(v[2]); o.s[3]=f2bf(v[3]);
  *(u64*)(dst + id) = o.q;
}

__global__ __launch_bounds__(256) void k_tr(const float* __restrict__ in, u16* __restrict__ out, int M, int N){
  __shared__ u16 t[64][65];
  int m0 = blockIdx.x << 6, n0 = blockIdx.y << 6;
  int c = threadIdx.x & 63, rq = threadIdx.x >> 6;
  for (int rr = 0; rr < 16; ++rr){
    int r = (rq << 4) + rr;
    t[r][c] = f2bf(in[(size_t)(m0 + r)*N + n0 + c]);
  }
  __syncthreads();
  for (int rr = 0; rr < 16; ++rr){
    int r = (rq << 4) + rr;
    out[(size_t)(n0 + r)*M + m0 + c] = t[c][r];
  }
}

// Fused weight build. jt4=1 (mode 0): each block covers 64 j-rows (4 tiles
// sharing one B-fragment -> B traffic /4). jt4=0: 16 j-rows (modes 1,2).
__global__ __launch_bounds__(256) void k_fuse(const float* __restrict__ Whh,
    const u16* __restrict__ Abf, const float* __restrict__ Wih,
    const u16* __restrict__ BT, int KM, int mode, int jt4, u16* __restrict__ dst)
{
  int bx = blockIdx.x, by = blockIdx.y, bz = blockIdx.z;
  int lane = threadIdx.x & 63, wv = threadIdx.x >> 6;
  int bl = lane & 15, kg = lane >> 4;
  int jbase = (mode == 0) ? bz*1024 : ((mode == 1) ? bz*320 : 0);
  int njt = jt4 ? 4 : 1;
  int k2c = by*64 + wv*16 + bl;
  f32x4 acc0={0,0,0,0}, acc1={0,0,0,0}, acc2={0,0,0,0}, acc3={0,0,0,0};
  for (int m0 = 0; m0 < KM; m0 += 32){
    FRAG bb; bb.v = *(const bf16x8*)(BT + (size_t)k2c*KM + m0 + (kg << 3));
    #pragma unroll
    for (int jt = 0; jt < 4; ++jt){
      if (jt >= njt) break;
      int jrow = jbase + bx*(16*njt) + jt*16 + bl;
      FRAG a;
      if (Abf){
        a.v = *(const bf16x8*)(Abf + (size_t)jrow*KM + m0 + (kg << 3));
      } else {
        f32x4 wa0 = *(const f32x4*)(Whh + (size_t)jrow*KM + m0 + (kg << 3));
        f32x4 wa1 = *(const f32x4*)(Whh + (size_t)jrow*KM + m0 + (kg << 3) + 4);
        a.s[0]=f2bf(wa0[0]); a.s[1]=f2bf(wa0[1]); a.s[2]=f2bf(wa0[2]); a.s[3]=f2bf(wa0[3]);
        a.s[4]=f2bf(wa1[0]); a.s[5]=f2bf(wa1[1]); a.s[6]=f2bf(wa1[2]); a.s[7]=f2bf(wa1[3]);
      }
      if (jt == 0) acc0 = MFMA16(a.v, bb.v, acc0);
      else if (jt == 1) acc1 = MFMA16(a.v, bb.v, acc1);
      else if (jt == 2) acc2 = MFMA16(a.v, bb.v, acc2);
      else acc3 = MFMA16(a.v, bb.v, acc3);
    }
  }
  #pragma unroll
  for (int jt = 0; jt < 4; ++jt){
    if (jt >= njt) break;
    f32x4 acc = (jt == 0) ? acc0 : (jt == 1) ? acc1 : (jt == 2) ? acc2 : acc3;
    #pragma unroll
    for (int r = 0; r < 4; ++r){
      int jl = (kg << 2) + r;
      int jg = jbase + bx*(16*njt) + jt*16 + jl;
      float v = acc[r];
      if (mode < 2) v += Wih[(size_t)jg*1024 + k2c];
      int tidx = bx*njt + jt;                 // 16-row tile index
      int re = (mode == 2) ? jl : (bz*16 + jl);
      int c = k2c >> 8, kl = k2c & 255;
      size_t pos;
      if (mode == 0)      pos = (size_t)tidx*81920 + c*20480 + re*256 + (kl ^ ((re&7)<<3));
      else if (mode == 1) pos = (size_t)tidx*65536 + c*16384 + re*256 + (kl ^ ((re&7)<<3));
      else                pos = (size_t)tidx*16384 + c*4096  + re*256 + (kl ^ ((re&7)<<3));
      dst[pos] = f2bf(v);
    }
  }
}

__global__ void k_pack_winh(const float* __restrict__ src, u16* __restrict__ dst){
  int id = blockIdx.x*256 + threadIdx.x;
  int j = id >> 10, k = id & 1023;
  int g = j >> 10, jj = j & 1023;
  int w = jj >> 4, r = (g << 4) + (jj & 15);
  int c = k >> 8, kl = k & 255;
  dst[(size_t)w*65536 + c*16384 + r*256 + (kl ^ ((r&7)<<3))] = f2bf(src[id]);
}

__global__ void k_pack_winx(const float* __restrict__ src, u16* __restrict__ dst){
  int j = blockIdx.x, k = threadIdx.x;
  int g = j >> 10, jj = j & 1023;
  int w = jj >> 4, r = (g << 4) + (jj & 15);
  float v = src[(size_t)j*320 + k];
  size_t pos;
  if (k < 256) pos = (size_t)w*20480 + r*256 + (k ^ ((r&7)<<3));
  else         pos = (size_t)w*20480 + 16384 + r*64 + ((k - 256) ^ ((r&7)<<3));
  dst[pos] = f2bf(v);
}

__global__ void k_pack_ca(const float* __restrict__ src, u16* __restrict__ dst){
  int id = blockIdx.x*256 + threadIdx.x;
  int jj = id >> 10, k = id & 1023;
  int w = jj >> 4, r = 64 + (jj & 15);
  int c = k >> 8, kl = k & 255;
  dst[(size_t)w*81920 + c*20480 + r*256 + (kl ^ ((r&7)<<3))] = f2bf(src[id]);
}

__global__ __launch_bounds__(256) void k_bias(const float* __restrict__ A, const float* __restrict__ x,
    const float* __restrict__ a1, const float* __restrict__ a2, float* __restrict__ o, int NJ, int K)
{
  int j = blockIdx.x*4 + (threadIdx.x >> 6);
  if (j >= NJ) return;
  int lane = threadIdx.x & 63;
  float acc = 0.f;
  if (A) for (int k = lane; k < K; k += 64) acc += A[(size_t)j*K + k]*x[k];
  for (int off = 32; off; off >>= 1) acc += __shfl_down(acc, off);
  if (lane == 0) o[j] = acc + (a1 ? a1[j] : 0.f) + (a2 ? a2[j] : 0.f);
}

// ---------------------------------------------------------------------------
extern "C" void kernel_launch(void* const* d_in, const int* in_sizes, int n_in,
                              void* d_out, int out_size, void* d_ws, size_t ws_size,
                              hipStream_t stream)
{
  (void)in_sizes; (void)n_in; (void)out_size;
  const float* z      = (const float*)d_in[0];
  const float* m_true = (const float*)d_in[1];
  const float* eh_W1=(const float*)d_in[2],  *eh_b1=(const float*)d_in[3];
  const float* eh_W2=(const float*)d_in[4],  *eh_b2=(const float*)d_in[5];
  const float* eh_W3=(const float*)d_in[6],  *eh_b3=(const float*)d_in[7];
  const float* ec_W1=(const float*)d_in[8],  *ec_b1=(const float*)d_in[9];
  const float* ec_W2=(const float*)d_in[10], *ec_b2=(const float*)d_in[11];
  const float* ec_W3=(const float*)d_in[12], *ec_b3=(const float*)d_in[13];
  const float* ex_W1=(const float*)d_in[14], *ex_b1=(const float*)d_in[15];
  const float* ex_W2=(const float*)d_in[16], *ex_b2=(const float*)d_in[17];
  const float* ex_W3=(const float*)d_in[18], *ex_b3=(const float*)d_in[19];
  const float* in_Wih=(const float*)d_in[20], *in_Whh=(const float*)d_in[21];
  const float* in_bih=(const float*)d_in[22], *in_bhh=(const float*)d_in[23];
  const float* r_Wih=(const float*)d_in[24],  *r_Whh=(const float*)d_in[25];
  const float* r_bih=(const float*)d_in[26],  *r_bhh=(const float*)d_in[27];
  const float* hA_W=(const float*)d_in[28],   *hA_b=(const float*)d_in[29];
  const float* cA_W=(const float*)d_in[30],   *cA_b=(const float*)d_in[31];
  const float* lastH_W=(const float*)d_in[32], *lastH_b=(const float*)d_in[33];
  const float* lastC_W=(const float*)d_in[34], *lastC_b=(const float*)d_in[35];
  const float* out_Wih=(const float*)d_in[36], *out_Whh=(const float*)d_in[37];
  const float* out_bih=(const float*)d_in[38], *out_bhh=(const float*)d_in[39];
  float* out = (float*)d_out;

  char* wsb = (char*)d_ws;
  size_t off = 0;
  auto alloc = [&](size_t bytes)->char*{
    char* p = wsb + off; off = (off + bytes + 255) & ~(size_t)255; return p;
  };
  u32* bar    = (u32*)alloc(256*32*4);
  u16* hS     = (u16*)alloc(2*64*1024*2);
  u16* cS     = (u16*)alloc(2*64*1024*2);
  float* cF   = (float*)alloc(64*1024*4);
  float* b_in = (float*)alloc(4096*4);
  float* b_cell=(float*)alloc(4*4096*4);
  float* b_out= (float*)alloc(1280*4);
  float* b_cc = (float*)alloc(320*4);
  float* t1   = (float*)alloc(1024*64*4);
  float* t2   = (float*)alloc(1024*64*4);
  u16* Tbuf   = (u16*)alloc((size_t)1024*1024*2);
  u16* Wbf    = (u16*)alloc((size_t)4096*1024*2);
  u16* Win_h  = (u16*)alloc((size_t)64*65536*2);
  u16* Win_x  = (u16*)alloc((size_t)64*20480*2);
  u16* Wcell  = (u16*)alloc((size_t)4*64*81920*2);
  u16* Wout   = (u16*)alloc((size_t)20*65536*2);
  u16* WccA   = (u16*)alloc((size_t)20*16384*2);
  if (off > ws_size) return;

  hipMemsetAsync(bar, 0, 256*32*4, stream);

  k_dense<<<256,256,0,stream>>>(z, 0, eh_W1, eh_b1, 1024, 256, 1, 0, t1, nullptr);
  k_dense<<<256,256,0,stream>>>(t1,1, eh_W2, eh_b2, 1024,1024, 1, 0, t2, nullptr);
  k_dense<<<256,256,0,stream>>>(t2,1, eh_W3, eh_b3, 1024,1024, 0, 1, nullptr, hS + 65536);
  k_dense<<<256,256,0,stream>>>(z, 0, ec_W1, ec_b1, 1024, 256, 1, 0, t1, nullptr);
  k_dense<<<256,256,0,stream>>>(t1,1, ec_W2, ec_b2, 1024,1024, 1, 0, t2, nullptr);
  k_dense<<<256,256,0,stream>>>(t2,1, ec_W3, ec_b3, 1024,1024, 0, 2, cF, nullptr);
  k_dense<<<256,256,0,stream>>>(z, 0, ex_W1, ex_b1, 1024, 256, 1, 0, t1, nullptr);
  k_dense<<<256,256,0,stream>>>(t1,1, ex_W2, ex_b2, 1024,1024, 1, 0, t2, nullptr);
  k_dense<<<16 ,256,0,stream>>>(t2,1, ex_W3, ex_b3,   64,1024, 0, 3, out, nullptr);
  k_zero0<<<64,256,0,stream>>>(out);

  k_pack_winh<<<16384,256,0,stream>>>(in_Whh, Win_h);
  k_pack_winx<<<4096,320,0,stream>>>(in_Wih, Win_x);
  for (int i = 0; i < 4; ++i)
    k_pack_ca<<<4096,256,0,stream>>>(cA_W + (size_t)i*1024*1024, Wcell + (size_t)i*64*81920);

  for (int i = 0; i < 4; ++i){
    k_cvt<<<4096,256,0,stream>>>(r_Whh + (size_t)i*4096*1024, Wbf);
    k_tr<<<dim3(16,16),256,0,stream>>>(hA_W + (size_t)i*1024*1024, Tbuf, 1024, 1024);
    k_fuse<<<dim3(16,16,4),256,0,stream>>>(nullptr, Wbf,
                                           r_Wih + (size_t)i*4096*1024,
                                           Tbuf, 1024, 0, 1, Wcell + (size_t)i*64*81920);
  }
  k_tr<<<dim3(5,16),256,0,stream>>>(lastH_W, Tbuf, 320, 1024);
  k_fuse<<<dim3(20,16,4),256,0,stream>>>(out_Whh, nullptr, out_Wih, Tbuf, 320, 1, 0, Wout);
  k_tr<<<dim3(16,16),256,0,stream>>>(cA_W + (size_t)3*1024*1024, Tbuf, 1024, 1024);
  k_fuse<<<dim3(20,16,1),256,0,stream>>>(lastC_W, nullptr, nullptr, Tbuf, 1024, 2, 0, WccA);

  k_bias<<<1024,256,0,stream>>>(nullptr, nullptr, in_bih, in_bhh, b_in, 4096, 0);
  for (int i = 0; i < 4; ++i)
    k_bias<<<1024,256,0,stream>>>(r_Whh + (size_t)i*4096*1024, hA_b + i*1024,
                                  r_bih + i*4096, r_bhh + i*4096, b_cell + i*4096, 4096, 1024);
  k_bias<<<320,256,0,stream>>>(out_Whh, lastH_b, out_bih, out_bhh, b_out, 1280, 320);
  k_bias<<<80 ,256,0,stream>>>(lastC_W, cA_b + 3*1024, lastC_b, nullptr, b_cc, 320, 1024);

  k_scan<<<NWG,256,0,stream>>>(m_true, Wcell, Win_h, Win_x, Wout, WccA,
                               b_in, b_cell, cA_b, b_out, b_cc,
                               hS, cS, cF, out, bar);
}